// Round 1
// baseline (10960.929 us; speedup 1.0000x reference)
//
#include <hip/hip_runtime.h>

// HeteroGNN fused fp32 baseline.
// Layout of workspace (floats): obj[N_OBJ*64] | agg[N_OBJ*64] | pooled[G*64]
//
// Per layer: memset agg; pred_kernel<R> for R=1,2,3 (fused gather+MLP+scatter-atomics);
// update_kernel (obj = MLP_u([obj|agg]) in-place). Then pool (atomics) + readout.

#define HID 64

// Tile matmul helper: Ax is LDS [64 x LDA] (row-major, LDA%4==0), W is global [DK x DN]
// row-major (fan_in x fan_out), Wc is LDS scratch [16 x DN]. Each thread owns 4 rows
// (mg, mg+16, mg+32, mg+48) x CPT cols starting at c0. Requires blockDim=256,
// DK%16==0, DN%16==0, CPT%4==0.
template<int DK, int DN, int LDA, int CPT>
__device__ __forceinline__ void mm_tile(const float* __restrict__ Ax,
                                        float* __restrict__ Wc,
                                        const float* __restrict__ W,
                                        int tid, int mg, int c0,
                                        float acc[4][CPT])
{
#pragma unroll
    for (int u = 0; u < 4; ++u)
#pragma unroll
        for (int j = 0; j < CPT; ++j) acc[u][j] = 0.f;

    for (int k0 = 0; k0 < DK; k0 += 16) {
        __syncthreads();  // previous chunk fully consumed (also covers Ax producer)
        // cooperative load of W[k0:k0+16][0:DN] into Wc
#pragma unroll
        for (int f = tid; f < 16 * DN / 4; f += 256) {
            int kk = f / (DN / 4), c4 = f % (DN / 4);
            ((float4*)Wc)[kk * (DN / 4) + c4] = ((const float4*)W)[(k0 + kk) * (DN / 4) + c4];
        }
        __syncthreads();
#pragma unroll
        for (int kk = 0; kk < 16; kk += 4) {
            float4 av[4];
#pragma unroll
            for (int u = 0; u < 4; ++u)
                av[u] = *(const float4*)(Ax + (mg + 16 * u) * LDA + k0 + kk);
#pragma unroll
            for (int kx = 0; kx < 4; ++kx) {
#pragma unroll
                for (int j4 = 0; j4 < CPT / 4; ++j4) {
                    float4 w4 = *(const float4*)(Wc + (kk + kx) * DN + c0 + 4 * j4);
#pragma unroll
                    for (int u = 0; u < 4; ++u) {
                        float a = (kx == 0) ? av[u].x : (kx == 1) ? av[u].y
                                 : (kx == 2) ? av[u].z : av[u].w;
                        acc[u][4 * j4 + 0] = fmaf(a, w4.x, acc[u][4 * j4 + 0]);
                        acc[u][4 * j4 + 1] = fmaf(a, w4.y, acc[u][4 * j4 + 1]);
                        acc[u][4 * j4 + 2] = fmaf(a, w4.z, acc[u][4 * j4 + 2]);
                        acc[u][4 * j4 + 3] = fmaf(a, w4.w, acc[u][4 * j4 + 3]);
                    }
                }
            }
        }
    }
}

// Fused per-predicate kernel: gather R obj-embeddings per atom, 2-layer MLP (d=64R),
// scatter-add R chunks of the output into agg via atomics.
template<int R>
__launch_bounds__(256)
__global__ void pred_kernel(const float* __restrict__ obj,
                            const int* __restrict__ ei,
                            const float* __restrict__ W1, const float* __restrict__ B1,
                            const float* __restrict__ W2, const float* __restrict__ B2,
                            float* __restrict__ agg, int n_atoms)
{
    constexpr int D = 64 * R;
    constexpr int LDA = D + 4;    // float4-aligned pad; banks spread (stride%32==4)
    constexpr int CPT = D / 16;
    __shared__ float Ax[64 * LDA];
    __shared__ float Wc[16 * D];
    __shared__ int eis[R * 64];

    const int tid = threadIdx.x;
    const int a_base = blockIdx.x * 64;
    const int mg = tid >> 4;    // 0..15
    const int cgi = tid & 15;   // 0..15
    const int c0 = cgi * CPT;

    for (int i = tid; i < R * 64; i += 256) {
        int s = i >> 6, a = i & 63;
        int ag = a_base + a; if (ag >= n_atoms) ag = n_atoms - 1;
        eis[s * 64 + a] = ei[s * n_atoms + ag];
    }
    __syncthreads();
    // gather: Ax[a][s*64 + 0..63] = obj[eis[s][a]]
#pragma unroll
    for (int f = tid; f < 64 * R * 16; f += 256) {
        int a = f / (R * 16);
        int rem = f % (R * 16);
        int s = rem >> 4, q = rem & 15;
        int o = eis[s * 64 + a];
        float4 v = ((const float4*)obj)[o * 16 + q];
        *(float4*)(Ax + a * LDA + s * 64 + 4 * q) = v;
    }
    float acc[4][CPT];
    mm_tile<D, D, LDA, CPT>(Ax, Wc, W1, tid, mg, c0, acc);
    __syncthreads();  // all reads of Ax done before overwrite with hidden
#pragma unroll
    for (int u = 0; u < 4; ++u) {
        int m = mg + 16 * u;
#pragma unroll
        for (int j = 0; j < CPT; ++j)
            Ax[m * LDA + c0 + j] = fmaxf(acc[u][j] + B1[c0 + j], 0.f);
    }
    // mm_tile's leading __syncthreads covers h visibility
    mm_tile<D, D, LDA, CPT>(Ax, Wc, W2, tid, mg, c0, acc);
#pragma unroll
    for (int u = 0; u < 4; ++u) {
        int m = mg + 16 * u;
        int ag = a_base + m;
        if (ag < n_atoms) {
#pragma unroll
            for (int j = 0; j < CPT; ++j) {
                int c = c0 + j;
                int o = eis[(c >> 6) * 64 + m];
                atomicAdd(agg + o * 64 + (c & 63), acc[u][j] + B2[c]);
            }
        }
    }
}

// obj = MLP_u(concat([obj, agg], 1)) : 128 -> 128 -> 64, in place (row-local).
__launch_bounds__(256)
__global__ void update_kernel(float* __restrict__ obj, const float* __restrict__ agg,
                              const float* __restrict__ W1, const float* __restrict__ B1,
                              const float* __restrict__ W2, const float* __restrict__ B2,
                              int n_obj)
{
    constexpr int LDA = 132;
    __shared__ float Ax[64 * LDA];
    __shared__ float Wc[16 * 128];
    const int tid = threadIdx.x;
    const int r_base = blockIdx.x * 64;
    const int mg = tid >> 4, cgi = tid & 15;

#pragma unroll
    for (int f = tid; f < 64 * 32; f += 256) {
        int a = f >> 5, q = f & 31;
        int rg = r_base + a; if (rg >= n_obj) rg = n_obj - 1;
        float4 v = (q < 16) ? ((const float4*)obj)[rg * 16 + q]
                            : ((const float4*)agg)[rg * 16 + (q - 16)];
        *(float4*)(Ax + a * LDA + 4 * q) = v;
    }
    float acc[4][8];
    mm_tile<128, 128, LDA, 8>(Ax, Wc, W1, tid, mg, cgi * 8, acc);
    __syncthreads();
#pragma unroll
    for (int u = 0; u < 4; ++u) {
        int m = mg + 16 * u;
#pragma unroll
        for (int j = 0; j < 8; ++j)
            Ax[m * LDA + cgi * 8 + j] = fmaxf(acc[u][j] + B1[cgi * 8 + j], 0.f);
    }
    float acc2[4][4];
    mm_tile<128, 64, LDA, 4>(Ax, Wc, W2, tid, mg, cgi * 4, acc2);
#pragma unroll
    for (int u = 0; u < 4; ++u) {
        int m = mg + 16 * u;
        int rg = r_base + m;
        if (rg < n_obj) {
#pragma unroll
            for (int j = 0; j < 4; ++j)
                obj[rg * 64 + cgi * 4 + j] = acc2[u][j] + B2[cgi * 4 + j];
        }
    }
}

__global__ void pool_kernel(const float* __restrict__ obj, const int* __restrict__ batch,
                            float* __restrict__ pooled, int n_obj)
{
    int i = blockIdx.x * 256 + threadIdx.x;
    int row = i >> 4, q = i & 15;
    if (row < n_obj) {
        float4 v = ((const float4*)obj)[row * 16 + q];
        int g = batch[row];
        float* p = pooled + g * 64 + 4 * q;
        atomicAdd(p + 0, v.x);
        atomicAdd(p + 1, v.y);
        atomicAdd(p + 2, v.z);
        atomicAdd(p + 3, v.w);
    }
}

// One block (128 threads) per graph: h = relu(pooled @ w1 + b1); out = h @ w2 + b2
__launch_bounds__(128)
__global__ void readout_kernel(const float* __restrict__ pooled,
                               const float* __restrict__ w1, const float* __restrict__ b1,
                               const float* __restrict__ w2, const float* __restrict__ b2,
                               float* __restrict__ out)
{
    int g = blockIdx.x, c = threadIdx.x;
    __shared__ float xs[64];
    __shared__ float red[2];
    if (c < 64) xs[c] = pooled[g * 64 + c];
    __syncthreads();
    float h = b1[c];
#pragma unroll
    for (int k = 0; k < 64; ++k) h = fmaf(xs[k], w1[k * 128 + c], h);
    float v = fmaxf(h, 0.f) * w2[c];
#pragma unroll
    for (int off = 32; off > 0; off >>= 1) v += __shfl_down(v, off);
    if ((c & 63) == 0) red[c >> 6] = v;
    __syncthreads();
    if (c == 0) out[g] = red[0] + red[1] + b2[0];
}

extern "C" void kernel_launch(void* const* d_in, const int* in_sizes, int n_in,
                              void* d_out, int out_size, void* d_ws, size_t ws_size,
                              hipStream_t stream)
{
    // input order per setup_inputs()
    const float* w_p1_1 = (const float*)d_in[4];
    const float* b_p1_1 = (const float*)d_in[5];
    const float* w_p1_2 = (const float*)d_in[6];
    const float* b_p1_2 = (const float*)d_in[7];
    const float* w_p2_1 = (const float*)d_in[8];
    const float* b_p2_1 = (const float*)d_in[9];
    const float* w_p2_2 = (const float*)d_in[10];
    const float* b_p2_2 = (const float*)d_in[11];
    const float* w_p3_1 = (const float*)d_in[12];
    const float* b_p3_1 = (const float*)d_in[13];
    const float* w_p3_2 = (const float*)d_in[14];
    const float* b_p3_2 = (const float*)d_in[15];
    const float* w_u1 = (const float*)d_in[16];
    const float* b_u1 = (const float*)d_in[17];
    const float* w_u2 = (const float*)d_in[18];
    const float* b_u2 = (const float*)d_in[19];
    const float* w_r1 = (const float*)d_in[20];
    const float* b_r1 = (const float*)d_in[21];
    const float* w_r2 = (const float*)d_in[22];
    const float* b_r2 = (const float*)d_in[23];
    const int* ei_p1 = (const int*)d_in[24];
    const int* ei_p2 = (const int*)d_in[25];
    const int* ei_p3 = (const int*)d_in[26];
    const int* batch = (const int*)d_in[27];

    const int n_obj = in_sizes[0];       // x_obj is [N_OBJ,1]
    const int n_p1 = in_sizes[24];       // ei_p1 is [1,N_P1]
    const int n_p2 = in_sizes[25] / 2;   // ei_p2 is [2,N_P2]
    const int n_p3 = in_sizes[26] / 3;   // ei_p3 is [3,N_P3]

    float* obj = (float*)d_ws;
    float* agg = obj + (size_t)n_obj * 64;
    float* pooled = agg + (size_t)n_obj * 64;

    hipMemsetAsync(obj, 0, (size_t)n_obj * 64 * sizeof(float), stream);
    for (int l = 0; l < 3; ++l) {
        hipMemsetAsync(agg, 0, (size_t)n_obj * 64 * sizeof(float), stream);
        pred_kernel<1><<<(n_p1 + 63) / 64, 256, 0, stream>>>(
            obj, ei_p1, w_p1_1, b_p1_1, w_p1_2, b_p1_2, agg, n_p1);
        pred_kernel<2><<<(n_p2 + 63) / 64, 256, 0, stream>>>(
            obj, ei_p2, w_p2_1, b_p2_1, w_p2_2, b_p2_2, agg, n_p2);
        pred_kernel<3><<<(n_p3 + 63) / 64, 256, 0, stream>>>(
            obj, ei_p3, w_p3_1, b_p3_1, w_p3_2, b_p3_2, agg, n_p3);
        update_kernel<<<(n_obj + 63) / 64, 256, 0, stream>>>(
            obj, agg, w_u1, b_u1, w_u2, b_u2, n_obj);
    }
    hipMemsetAsync(pooled, 0, (size_t)out_size * 64 * sizeof(float), stream);
    pool_kernel<<<((size_t)n_obj * 16 + 255) / 256, 256, 0, stream>>>(obj, batch, pooled, n_obj);
    readout_kernel<<<out_size, 128, 0, stream>>>(pooled, w_r1, b_r1, w_r2, b_r2, (float*)d_out);
}

// Round 2
// 3884.284 us; speedup vs baseline: 2.8219x; 2.8219x over previous
//
#include <hip/hip_runtime.h>

typedef _Float16 half8 __attribute__((ext_vector_type(8)));
typedef float f32x4 __attribute__((ext_vector_type(4)));
typedef unsigned int uint;
typedef unsigned short ushort;

// ---- fp16 split-precision helpers: x ~= hi + lo, each fp16; packed as u32 ----
__device__ __forceinline__ uint pack2(float x) {
    _Float16 h = (_Float16)x;
    _Float16 l = (_Float16)(x - (float)h);
    return (uint)__builtin_bit_cast(ushort, h) | ((uint)__builtin_bit_cast(ushort, l) << 16);
}

__device__ __forceinline__ void unpack8(uint4 w0, uint4 w1, half8& hi, half8& lo) {
    uint w[8] = {w0.x, w0.y, w0.z, w0.w, w1.x, w1.y, w1.z, w1.w};
#pragma unroll
    for (int j = 0; j < 8; ++j) {
        hi[j] = __builtin_bit_cast(_Float16, (ushort)(w[j] & 0xffffu));
        lo[j] = __builtin_bit_cast(_Float16, (ushort)(w[j] >> 16));
    }
}

// 3-term split-product MFMA: A*B ~= AhBh + AhBl + AlBh (drop AlBl ~ 2^-22 rel)
__device__ __forceinline__ f32x4 mfma3(half8 ah, half8 al, half8 bh, half8 bl, f32x4 c) {
    c = __builtin_amdgcn_mfma_f32_16x16x32_f16(ah, bh, c, 0, 0, 0);
    c = __builtin_amdgcn_mfma_f32_16x16x32_f16(ah, bl, c, 0, 0, 0);
    c = __builtin_amdgcn_mfma_f32_16x16x32_f16(al, bh, c, 0, 0, 0);
    return c;
}

// ---- weight prep: Wp[n][k] = pack2(W[k][n])  (transpose + split + pack) ----
__launch_bounds__(256)
__global__ void wprep(const float* __restrict__ w_p1_1, const float* __restrict__ w_p1_2,
                      const float* __restrict__ w_p2_1, const float* __restrict__ w_p2_2,
                      const float* __restrict__ w_p3_1, const float* __restrict__ w_p3_2,
                      const float* __restrict__ w_u1, const float* __restrict__ w_u2,
                      uint* __restrict__ d_p1_1, uint* __restrict__ d_p1_2,
                      uint* __restrict__ d_p2_1, uint* __restrict__ d_p2_2,
                      uint* __restrict__ d_p3_1, uint* __restrict__ d_p3_2,
                      uint* __restrict__ d_u1, uint* __restrict__ d_u2)
{
    int b = blockIdx.x;
    const float* src; uint* dst; int K, N, base;
    if      (b < 16)  { src = w_p1_1; dst = d_p1_1; K = 64;  N = 64;  base = 0;   }
    else if (b < 32)  { src = w_p1_2; dst = d_p1_2; K = 64;  N = 64;  base = 16;  }
    else if (b < 96)  { src = w_p2_1; dst = d_p2_1; K = 128; N = 128; base = 32;  }
    else if (b < 160) { src = w_p2_2; dst = d_p2_2; K = 128; N = 128; base = 96;  }
    else if (b < 304) { src = w_p3_1; dst = d_p3_1; K = 192; N = 192; base = 160; }
    else if (b < 448) { src = w_p3_2; dst = d_p3_2; K = 192; N = 192; base = 304; }
    else if (b < 512) { src = w_u1;   dst = d_u1;   K = 128; N = 128; base = 448; }
    else              { src = w_u2;   dst = d_u2;   K = 128; N = 64;  base = 512; }
    int e = (b - base) * 256 + threadIdx.x;
    if (e < K * N) {
        int n = e / K, k = e - n * K;
        dst[e] = pack2(src[k * N + n]);
    }
}

// ---- fused per-predicate kernel, wave-local 16-atom tiles, NO __syncthreads ----
// gather(obj rows via ei) -> GEMM1(+b1,relu) -> GEMM2(+b2) -> atomic scatter to agg
template<int R>
__launch_bounds__(256)
__global__ void pred_mfma(const float* __restrict__ obj, const int* __restrict__ ei,
                          const uint* __restrict__ W1p, const float* __restrict__ B1,
                          const uint* __restrict__ W2p, const float* __restrict__ B2,
                          float* __restrict__ agg, int n_atoms)
{
    constexpr int D = 64 * R;
    constexpr int NT = D / 16;    // 16-col output tiles
    constexpr int KC = D / 32;    // K chunks of 32
    constexpr int LDA = D + 4;    // u32 row stride (bank offset 4 mod 32)
    __shared__ uint Ax[64 * LDA];

    const int tid = threadIdx.x;
    const int wave = tid >> 6, lane = tid & 63;
    const int r = lane & 15, g = lane >> 4;
    const int a0 = blockIdx.x * 64 + wave * 16;   // wave's first atom
    uint* const Aw = Ax + wave * 16 * LDA;        // wave-private 16-row slice

    // ---- gather: Aw[r][s*64 + c] = packed(obj[ei[s][a0+r]][c]) ----
    {
        int atom = a0 + r;
        int ac = atom < n_atoms ? atom : (n_atoms - 1);
        const float4* obj4 = (const float4*)obj;
        uint* Arow = Aw + r * LDA;
        int pp = (g + r) & 3;   // swizzled quarter to spread LDS banks
#pragma unroll
        for (int s = 0; s < R; ++s) {
            int o = ei[s * n_atoms + ac];
            const float4* src = obj4 + (size_t)o * 16;
#pragma unroll
            for (int i = 0; i < 4; ++i) {
                float4 v = src[pp + 4 * i];
                uint4 u = make_uint4(pack2(v.x), pack2(v.y), pack2(v.z), pack2(v.w));
                *(uint4*)(Arow + s * 64 + 4 * (pp + 4 * i)) = u;
            }
        }
    }
    __builtin_amdgcn_wave_barrier();

    f32x4 z = {0.f, 0.f, 0.f, 0.f};
    f32x4 acc[NT];
#pragma unroll
    for (int t = 0; t < NT; ++t) acc[t] = z;

    // ---- GEMM1: [16 x D] * [D x D] ----
#pragma unroll
    for (int kc = 0; kc < KC; ++kc) {
        const uint* ap = Aw + r * LDA + kc * 32 + g * 8;
        half8 ah, al;
        unpack8(*(const uint4*)ap, *(const uint4*)(ap + 4), ah, al);
#pragma unroll
        for (int t = 0; t < NT; ++t) {
            const uint* bp = W1p + (size_t)(t * 16 + r) * D + kc * 32 + g * 8;
            half8 bh, bl;
            unpack8(*(const uint4*)bp, *(const uint4*)(bp + 4), bh, bl);
            acc[t] = mfma3(ah, al, bh, bl, acc[t]);
        }
    }
    __builtin_amdgcn_wave_barrier();

    // ---- epilogue1: relu(acc + b1) packed back into Aw (wave-local reuse) ----
#pragma unroll
    for (int t = 0; t < NT; ++t) {
        int col = t * 16 + r;
        float b1 = B1[col];
#pragma unroll
        for (int q = 0; q < 4; ++q) {
            int row = g * 4 + q;
            float h = acc[t][q] + b1;
            h = h > 0.f ? h : 0.f;
            Aw[row * LDA + col] = pack2(h);
        }
    }
    __builtin_amdgcn_wave_barrier();

    // ---- GEMM2: [16 x D] * [D x D] ----
#pragma unroll
    for (int t = 0; t < NT; ++t) acc[t] = z;
#pragma unroll
    for (int kc = 0; kc < KC; ++kc) {
        const uint* ap = Aw + r * LDA + kc * 32 + g * 8;
        half8 ah, al;
        unpack8(*(const uint4*)ap, *(const uint4*)(ap + 4), ah, al);
#pragma unroll
        for (int t = 0; t < NT; ++t) {
            const uint* bp = W2p + (size_t)(t * 16 + r) * D + kc * 32 + g * 8;
            half8 bh, bl;
            unpack8(*(const uint4*)bp, *(const uint4*)(bp + 4), bh, bl);
            acc[t] = mfma3(ah, al, bh, bl, acc[t]);
        }
    }

    // ---- scatter: atomicAdd chunks into agg ----
    int eo[R][4];
#pragma unroll
    for (int s = 0; s < R; ++s)
#pragma unroll
        for (int q = 0; q < 4; ++q) {
            int atom = a0 + g * 4 + q;
            eo[s][q] = ei[s * n_atoms + (atom < n_atoms ? atom : 0)];
        }
#pragma unroll
    for (int t = 0; t < NT; ++t) {
        int col = t * 16 + r;
        float b2 = B2[col];
        int s = col >> 6, cc = col & 63;
#pragma unroll
        for (int q = 0; q < 4; ++q) {
            int atom = a0 + g * 4 + q;
            if (atom < n_atoms)
                atomicAdd(agg + (size_t)eo[s][q] * 64 + cc, acc[t][q] + b2);
        }
    }
}

// ---- obj update: obj = MLP_u([obj|agg]) 128->128(relu)->64, wave-local ----
__launch_bounds__(256)
__global__ void update_mfma(float* __restrict__ obj, const float* __restrict__ agg,
                            const uint* __restrict__ W1p, const float* __restrict__ B1,
                            const uint* __restrict__ W2p, const float* __restrict__ B2,
                            int n_obj)
{
    constexpr int LDA = 132;
    __shared__ uint Ax[64 * LDA];

    const int tid = threadIdx.x;
    const int wave = tid >> 6, lane = tid & 63;
    const int r = lane & 15, g = lane >> 4;
    const int a0 = blockIdx.x * 64 + wave * 16;
    uint* const Aw = Ax + wave * 16 * LDA;

    // assemble [obj | agg] row, packed
    {
        int row = a0 + r;
        int rc = row < n_obj ? row : (n_obj - 1);
        const float4* o4 = (const float4*)obj;
        const float4* g4 = (const float4*)agg;
        uint* Arow = Aw + r * LDA;
        int pp = (g + r) & 3;
#pragma unroll
        for (int i = 0; i < 8; ++i) {
            int q = pp + 4 * i;  // 0..31 quarter-strided
            float4 v = (q < 16) ? o4[(size_t)rc * 16 + q] : g4[(size_t)rc * 16 + (q - 16)];
            uint4 u = make_uint4(pack2(v.x), pack2(v.y), pack2(v.z), pack2(v.w));
            *(uint4*)(Arow + 4 * q) = u;
        }
    }
    __builtin_amdgcn_wave_barrier();

    f32x4 z = {0.f, 0.f, 0.f, 0.f};
    f32x4 acc[8];
#pragma unroll
    for (int t = 0; t < 8; ++t) acc[t] = z;
#pragma unroll
    for (int kc = 0; kc < 4; ++kc) {
        const uint* ap = Aw + r * LDA + kc * 32 + g * 8;
        half8 ah, al;
        unpack8(*(const uint4*)ap, *(const uint4*)(ap + 4), ah, al);
#pragma unroll
        for (int t = 0; t < 8; ++t) {
            const uint* bp = W1p + (size_t)(t * 16 + r) * 128 + kc * 32 + g * 8;
            half8 bh, bl;
            unpack8(*(const uint4*)bp, *(const uint4*)(bp + 4), bh, bl);
            acc[t] = mfma3(ah, al, bh, bl, acc[t]);
        }
    }
    __builtin_amdgcn_wave_barrier();
#pragma unroll
    for (int t = 0; t < 8; ++t) {
        int col = t * 16 + r;
        float b1 = B1[col];
#pragma unroll
        for (int q = 0; q < 4; ++q) {
            int row = g * 4 + q;
            float h = acc[t][q] + b1;
            h = h > 0.f ? h : 0.f;
            Aw[row * LDA + col] = pack2(h);
        }
    }
    __builtin_amdgcn_wave_barrier();

    f32x4 acc2[4];
#pragma unroll
    for (int t = 0; t < 4; ++t) acc2[t] = z;
#pragma unroll
    for (int kc = 0; kc < 4; ++kc) {
        const uint* ap = Aw + r * LDA + kc * 32 + g * 8;
        half8 ah, al;
        unpack8(*(const uint4*)ap, *(const uint4*)(ap + 4), ah, al);
#pragma unroll
        for (int t = 0; t < 4; ++t) {
            const uint* bp = W2p + (size_t)(t * 16 + r) * 128 + kc * 32 + g * 8;
            half8 bh, bl;
            unpack8(*(const uint4*)bp, *(const uint4*)(bp + 4), bh, bl);
            acc2[t] = mfma3(ah, al, bh, bl, acc2[t]);
        }
    }
#pragma unroll
    for (int t = 0; t < 4; ++t) {
        int col = t * 16 + r;
        float b2 = B2[col];
#pragma unroll
        for (int q = 0; q < 4; ++q) {
            int row = a0 + g * 4 + q;
            if (row < n_obj)
                obj[(size_t)row * 64 + col] = acc2[t][q] + b2;
        }
    }
}

__global__ void pool_kernel(const float* __restrict__ obj, const int* __restrict__ batch,
                            float* __restrict__ pooled, int n_obj)
{
    int i = blockIdx.x * 256 + threadIdx.x;
    int row = i >> 4, q = i & 15;
    if (row < n_obj) {
        float4 v = ((const float4*)obj)[(size_t)row * 16 + q];
        int g = batch[row];
        float* p = pooled + g * 64 + 4 * q;
        atomicAdd(p + 0, v.x);
        atomicAdd(p + 1, v.y);
        atomicAdd(p + 2, v.z);
        atomicAdd(p + 3, v.w);
    }
}

__launch_bounds__(128)
__global__ void readout_kernel(const float* __restrict__ pooled,
                               const float* __restrict__ w1, const float* __restrict__ b1,
                               const float* __restrict__ w2, const float* __restrict__ b2,
                               float* __restrict__ out)
{
    int g = blockIdx.x, c = threadIdx.x;
    __shared__ float xs[64];
    __shared__ float red[2];
    if (c < 64) xs[c] = pooled[g * 64 + c];
    __syncthreads();
    float h = b1[c];
#pragma unroll
    for (int k = 0; k < 64; ++k) h = fmaf(xs[k], w1[k * 128 + c], h);
    float v = fmaxf(h, 0.f) * w2[c];
#pragma unroll
    for (int off = 32; off > 0; off >>= 1) v += __shfl_down(v, off);
    if ((c & 63) == 0) red[c >> 6] = v;
    __syncthreads();
    if (c == 0) out[g] = red[0] + red[1] + b2[0];
}

extern "C" void kernel_launch(void* const* d_in, const int* in_sizes, int n_in,
                              void* d_out, int out_size, void* d_ws, size_t ws_size,
                              hipStream_t stream)
{
    const float* w_p1_1 = (const float*)d_in[4];
    const float* b_p1_1 = (const float*)d_in[5];
    const float* w_p1_2 = (const float*)d_in[6];
    const float* b_p1_2 = (const float*)d_in[7];
    const float* w_p2_1 = (const float*)d_in[8];
    const float* b_p2_1 = (const float*)d_in[9];
    const float* w_p2_2 = (const float*)d_in[10];
    const float* b_p2_2 = (const float*)d_in[11];
    const float* w_p3_1 = (const float*)d_in[12];
    const float* b_p3_1 = (const float*)d_in[13];
    const float* w_p3_2 = (const float*)d_in[14];
    const float* b_p3_2 = (const float*)d_in[15];
    const float* w_u1 = (const float*)d_in[16];
    const float* b_u1 = (const float*)d_in[17];
    const float* w_u2 = (const float*)d_in[18];
    const float* b_u2 = (const float*)d_in[19];
    const float* w_r1 = (const float*)d_in[20];
    const float* b_r1 = (const float*)d_in[21];
    const float* w_r2 = (const float*)d_in[22];
    const float* b_r2 = (const float*)d_in[23];
    const int* ei_p1 = (const int*)d_in[24];
    const int* ei_p2 = (const int*)d_in[25];
    const int* ei_p3 = (const int*)d_in[26];
    const int* batch = (const int*)d_in[27];

    const int n_obj = in_sizes[0];
    const int n_p1 = in_sizes[24];
    const int n_p2 = in_sizes[25] / 2;
    const int n_p3 = in_sizes[26] / 3;

    float* obj = (float*)d_ws;
    float* agg = obj + (size_t)n_obj * 64;
    float* pooled = agg + (size_t)n_obj * 64;
    uint* wbuf = (uint*)(pooled + (size_t)out_size * 64);
    uint* d_p1_1 = wbuf;             // 64*64
    uint* d_p1_2 = d_p1_1 + 4096;    // 64*64
    uint* d_p2_1 = d_p1_2 + 4096;    // 128*128
    uint* d_p2_2 = d_p2_1 + 16384;   // 128*128
    uint* d_p3_1 = d_p2_2 + 16384;   // 192*192
    uint* d_p3_2 = d_p3_1 + 36864;   // 192*192
    uint* d_u1   = d_p3_2 + 36864;   // 128*128
    uint* d_u2   = d_u1 + 16384;     // 128*64

    wprep<<<544, 256, 0, stream>>>(w_p1_1, w_p1_2, w_p2_1, w_p2_2, w_p3_1, w_p3_2,
                                   w_u1, w_u2,
                                   d_p1_1, d_p1_2, d_p2_1, d_p2_2, d_p3_1, d_p3_2,
                                   d_u1, d_u2);
    hipMemsetAsync(obj, 0, (size_t)n_obj * 64 * sizeof(float), stream);
    for (int l = 0; l < 3; ++l) {
        hipMemsetAsync(agg, 0, (size_t)n_obj * 64 * sizeof(float), stream);
        pred_mfma<1><<<(n_p1 + 63) / 64, 256, 0, stream>>>(
            obj, ei_p1, d_p1_1, b_p1_1, d_p1_2, b_p1_2, agg, n_p1);
        pred_mfma<2><<<(n_p2 + 63) / 64, 256, 0, stream>>>(
            obj, ei_p2, d_p2_1, b_p2_1, d_p2_2, b_p2_2, agg, n_p2);
        pred_mfma<3><<<(n_p3 + 63) / 64, 256, 0, stream>>>(
            obj, ei_p3, d_p3_1, b_p3_1, d_p3_2, b_p3_2, agg, n_p3);
        update_mfma<<<(n_obj + 63) / 64, 256, 0, stream>>>(
            obj, agg, d_u1, b_u1, d_u2, b_u2, n_obj);
    }
    hipMemsetAsync(pooled, 0, (size_t)out_size * 64 * sizeof(float), stream);
    pool_kernel<<<((size_t)n_obj * 16 + 255) / 256, 256, 0, stream>>>(obj, batch, pooled, n_obj);
    readout_kernel<<<out_size, 128, 0, stream>>>(pooled, w_r1, b_r1, w_r2, b_r2, (float*)d_out);
}

// Round 4
// 2126.932 us; speedup vs baseline: 5.1534x; 1.8262x over previous
//
#include <hip/hip_runtime.h>

typedef _Float16 h8 __attribute__((ext_vector_type(8)));
typedef _Float16 h4 __attribute__((ext_vector_type(4)));
typedef float f32x4 __attribute__((ext_vector_type(4)));
typedef unsigned int uint;

// 3-term split-product MFMA: A*B ~= AhBh + AhBl + AlBh (drop AlBl ~ 2^-22 rel)
__device__ __forceinline__ f32x4 mfma3(h8 ah, h8 al, h8 bh, h8 bl, f32x4 c) {
    c = __builtin_amdgcn_mfma_f32_16x16x32_f16(ah, bh, c, 0, 0, 0);
    c = __builtin_amdgcn_mfma_f32_16x16x32_f16(ah, bl, c, 0, 0, 0);
    c = __builtin_amdgcn_mfma_f32_16x16x32_f16(al, bh, c, 0, 0, 0);
    return c;
}

// ---- weight prep: for W[K][N] (row-major), store hi/lo fp16 planes n-major:
//      hb[off + n*K + k] = (h16)W[k][n];  hb[off + K*N + n*K + k] = lo residual
__launch_bounds__(256)
__global__ void wprep(const float* __restrict__ w_p1_1, const float* __restrict__ w_p1_2,
                      const float* __restrict__ w_p2_1, const float* __restrict__ w_p2_2,
                      const float* __restrict__ w_p3_1, const float* __restrict__ w_p3_2,
                      const float* __restrict__ w_u1, const float* __restrict__ w_u2,
                      _Float16* __restrict__ hb)
{
    int b = blockIdx.x;
    const float* src; int K, N, base; size_t off;
    if      (b < 16)  { src = w_p1_1; K = 64;  N = 64;  base = 0;   off = 0;      }
    else if (b < 32)  { src = w_p1_2; K = 64;  N = 64;  base = 16;  off = 8192;   }
    else if (b < 96)  { src = w_p2_1; K = 128; N = 128; base = 32;  off = 16384;  }
    else if (b < 160) { src = w_p2_2; K = 128; N = 128; base = 96;  off = 49152;  }
    else if (b < 304) { src = w_p3_1; K = 192; N = 192; base = 160; off = 81920;  }
    else if (b < 448) { src = w_p3_2; K = 192; N = 192; base = 304; off = 155648; }
    else if (b < 512) { src = w_u1;   K = 128; N = 128; base = 448; off = 229376; }
    else              { src = w_u2;   K = 128; N = 64;  base = 512; off = 262144; }
    int e = (b - base) * 256 + threadIdx.x;
    if (e < K * N) {
        int n = e / K, k = e - n * K;
        float x = src[k * N + n];
        _Float16 h = (_Float16)x;
        hb[off + e] = h;
        hb[off + (size_t)K * N + e] = (_Float16)(x - (float)h);
    }
}

// ---- fused per-predicate kernel ----
// block = 64 atoms, 4 waves; wave w computes ALL 64 rows x col-tiles [w*R .. w*R+R)
// gather -> GEMM1(+b1,relu via LDS) -> GEMM2(+b2) -> atomic scatter into agg
template<int R>
__launch_bounds__(256)
__global__ void pred_mfma(const float* __restrict__ obj, const int* __restrict__ ei,
                          const _Float16* __restrict__ W1h, const _Float16* __restrict__ W1l,
                          const float* __restrict__ B1,
                          const _Float16* __restrict__ W2h, const _Float16* __restrict__ W2l,
                          const float* __restrict__ B2,
                          float* __restrict__ agg, int n_atoms)
{
    constexpr int D = 64 * R;
    constexpr int NT4 = R;        // col tiles per wave = (D/16)/4
    constexpr int KC = D / 32;
    constexpr int LDA = D + 8;    // fp16 elements; row = LDA*2 bytes (16B-aligned)
    __shared__ _Float16 Ah[64 * LDA];
    __shared__ _Float16 Al[64 * LDA];
    __shared__ int eis[R * 64];

    const int tid = threadIdx.x;
    const int wave = tid >> 6, lane = tid & 63;
    const int r = lane & 15, g = lane >> 4;
    const int a_base = blockIdx.x * 64;
    const int tb = wave * NT4;

    for (int i = tid; i < R * 64; i += 256) {
        int s = i >> 6, a = i & 63;
        int ag = a_base + a; if (ag >= n_atoms) ag = n_atoms - 1;
        eis[i] = ei[s * n_atoms + ag];
    }
    __syncthreads();
    // gather + split into hi/lo planes
    {
        const float4* obj4 = (const float4*)obj;
#pragma unroll
        for (int i = 0; i < 4 * R; ++i) {
            int f = tid + 256 * i;
            int a = f / (R * 16), rem = f % (R * 16);
            int s = rem >> 4, q = rem & 15;
            float4 v = obj4[(size_t)eis[s * 64 + a] * 16 + q];
            _Float16 h0 = (_Float16)v.x, h1 = (_Float16)v.y,
                     h2 = (_Float16)v.z, h3 = (_Float16)v.w;
            h4 hv = {h0, h1, h2, h3};
            h4 lv = {(_Float16)(v.x - (float)h0), (_Float16)(v.y - (float)h1),
                     (_Float16)(v.z - (float)h2), (_Float16)(v.w - (float)h3)};
            *(h4*)(Ah + a * LDA + s * 64 + 4 * q) = hv;
            *(h4*)(Al + a * LDA + s * 64 + 4 * q) = lv;
        }
    }
    __syncthreads();

    f32x4 z = {0.f, 0.f, 0.f, 0.f};
    f32x4 acc[4][NT4];
#pragma unroll
    for (int rt = 0; rt < 4; ++rt)
#pragma unroll
        for (int t = 0; t < NT4; ++t) acc[rt][t] = z;

    // ---- GEMM1 ----
#pragma unroll
    for (int kc = 0; kc < KC; ++kc) {
        const int ko = kc * 32 + g * 8;
        h8 ah[4], al[4];
#pragma unroll
        for (int rt = 0; rt < 4; ++rt) {
            ah[rt] = *(const h8*)(Ah + (rt * 16 + r) * LDA + ko);
            al[rt] = *(const h8*)(Al + (rt * 16 + r) * LDA + ko);
        }
#pragma unroll
        for (int t = 0; t < NT4; ++t) {
            size_t wo = (size_t)((tb + t) * 16 + r) * D + ko;
            h8 bh = *(const h8*)(W1h + wo);
            h8 bl = *(const h8*)(W1l + wo);
#pragma unroll
            for (int rt = 0; rt < 4; ++rt)
                acc[rt][t] = mfma3(ah[rt], al[rt], bh, bl, acc[rt][t]);
        }
    }
    __syncthreads();   // all waves done reading A before hidden overwrite

    // ---- epilogue 1: relu(acc+b1) -> hi/lo back into Ah/Al ----
#pragma unroll
    for (int t = 0; t < NT4; ++t) {
        int col = (tb + t) * 16 + r;
        float b1 = B1[col];
#pragma unroll
        for (int rt = 0; rt < 4; ++rt)
#pragma unroll
            for (int q = 0; q < 4; ++q) {
                int row = rt * 16 + g * 4 + q;
                float h = acc[rt][t][q] + b1;
                h = h > 0.f ? h : 0.f;
                _Float16 hh = (_Float16)h;
                Ah[row * LDA + col] = hh;
                Al[row * LDA + col] = (_Float16)(h - (float)hh);
            }
    }
    __syncthreads();

    // ---- GEMM2 ----
#pragma unroll
    for (int rt = 0; rt < 4; ++rt)
#pragma unroll
        for (int t = 0; t < NT4; ++t) acc[rt][t] = z;
#pragma unroll
    for (int kc = 0; kc < KC; ++kc) {
        const int ko = kc * 32 + g * 8;
        h8 ah[4], al[4];
#pragma unroll
        for (int rt = 0; rt < 4; ++rt) {
            ah[rt] = *(const h8*)(Ah + (rt * 16 + r) * LDA + ko);
            al[rt] = *(const h8*)(Al + (rt * 16 + r) * LDA + ko);
        }
#pragma unroll
        for (int t = 0; t < NT4; ++t) {
            size_t wo = (size_t)((tb + t) * 16 + r) * D + ko;
            h8 bh = *(const h8*)(W2h + wo);
            h8 bl = *(const h8*)(W2l + wo);
#pragma unroll
            for (int rt = 0; rt < 4; ++rt)
                acc[rt][t] = mfma3(ah[rt], al[rt], bh, bl, acc[rt][t]);
        }
    }

    // ---- scatter ----
#pragma unroll
    for (int t = 0; t < NT4; ++t) {
        int col = (tb + t) * 16 + r;
        float b2 = B2[col];
        int s = col >> 6, cc = col & 63;
#pragma unroll
        for (int rt = 0; rt < 4; ++rt)
#pragma unroll
            for (int q = 0; q < 4; ++q) {
                int row = rt * 16 + g * 4 + q;
                int atom = a_base + row;
                if (atom < n_atoms)
                    atomicAdd(agg + (size_t)eis[s * 64 + row] * 64 + cc,
                              acc[rt][t][q] + b2);
            }
    }
}

// ---- obj update: obj = MLP_u([obj|agg]) 128->128(relu)->64 ----
__launch_bounds__(256)
__global__ void update_mfma(float* __restrict__ obj, const float* __restrict__ agg,
                            const _Float16* __restrict__ W1h, const _Float16* __restrict__ W1l,
                            const float* __restrict__ B1,
                            const _Float16* __restrict__ W2h, const _Float16* __restrict__ W2l,
                            const float* __restrict__ B2,
                            int n_obj)
{
    constexpr int LDA = 136;
    __shared__ _Float16 Ah[64 * LDA];
    __shared__ _Float16 Al[64 * LDA];

    const int tid = threadIdx.x;
    const int wave = tid >> 6, lane = tid & 63;
    const int r = lane & 15, g = lane >> 4;
    const int a_base = blockIdx.x * 64;

    {
        const float4* o4 = (const float4*)obj;
        const float4* g4 = (const float4*)agg;
#pragma unroll
        for (int i = 0; i < 8; ++i) {
            int f = tid + 256 * i;
            int a = f >> 5, q = f & 31;
            int rg = a_base + a; if (rg >= n_obj) rg = n_obj - 1;
            float4 v = (q < 16) ? o4[(size_t)rg * 16 + q] : g4[(size_t)rg * 16 + (q - 16)];
            _Float16 h0 = (_Float16)v.x, h1 = (_Float16)v.y,
                     h2 = (_Float16)v.z, h3 = (_Float16)v.w;
            h4 hv = {h0, h1, h2, h3};
            h4 lv = {(_Float16)(v.x - (float)h0), (_Float16)(v.y - (float)h1),
                     (_Float16)(v.z - (float)h2), (_Float16)(v.w - (float)h3)};
            *(h4*)(Ah + a * LDA + 4 * q) = hv;
            *(h4*)(Al + a * LDA + 4 * q) = lv;
        }
    }
    __syncthreads();

    f32x4 z = {0.f, 0.f, 0.f, 0.f};
    f32x4 acc[4][2];
#pragma unroll
    for (int rt = 0; rt < 4; ++rt) { acc[rt][0] = z; acc[rt][1] = z; }
#pragma unroll
    for (int kc = 0; kc < 4; ++kc) {
        const int ko = kc * 32 + g * 8;
        h8 ah[4], al[4];
#pragma unroll
        for (int rt = 0; rt < 4; ++rt) {
            ah[rt] = *(const h8*)(Ah + (rt * 16 + r) * LDA + ko);
            al[rt] = *(const h8*)(Al + (rt * 16 + r) * LDA + ko);
        }
#pragma unroll
        for (int t = 0; t < 2; ++t) {
            size_t wo = (size_t)((wave * 2 + t) * 16 + r) * 128 + ko;
            h8 bh = *(const h8*)(W1h + wo);
            h8 bl = *(const h8*)(W1l + wo);
#pragma unroll
            for (int rt = 0; rt < 4; ++rt)
                acc[rt][t] = mfma3(ah[rt], al[rt], bh, bl, acc[rt][t]);
        }
    }
    __syncthreads();
#pragma unroll
    for (int t = 0; t < 2; ++t) {
        int col = (wave * 2 + t) * 16 + r;
        float b1 = B1[col];
#pragma unroll
        for (int rt = 0; rt < 4; ++rt)
#pragma unroll
            for (int q = 0; q < 4; ++q) {
                int row = rt * 16 + g * 4 + q;
                float h = acc[rt][t][q] + b1;
                h = h > 0.f ? h : 0.f;
                _Float16 hh = (_Float16)h;
                Ah[row * LDA + col] = hh;
                Al[row * LDA + col] = (_Float16)(h - (float)hh);
            }
    }
    __syncthreads();

    f32x4 acc2[4];
#pragma unroll
    for (int rt = 0; rt < 4; ++rt) acc2[rt] = z;
#pragma unroll
    for (int kc = 0; kc < 4; ++kc) {
        const int ko = kc * 32 + g * 8;
#pragma unroll
        for (int rt = 0; rt < 4; ++rt) {
            h8 ah = *(const h8*)(Ah + (rt * 16 + r) * LDA + ko);
            h8 al = *(const h8*)(Al + (rt * 16 + r) * LDA + ko);
            size_t wo = (size_t)(wave * 16 + r) * 128 + ko;
            h8 bh = *(const h8*)(W2h + wo);
            h8 bl = *(const h8*)(W2l + wo);
            acc2[rt] = mfma3(ah, al, bh, bl, acc2[rt]);
        }
    }
    {
        int col = wave * 16 + r;
        float b2 = B2[col];
#pragma unroll
        for (int rt = 0; rt < 4; ++rt)
#pragma unroll
            for (int q = 0; q < 4; ++q) {
                int row = a_base + rt * 16 + g * 4 + q;
                if (row < n_obj)
                    obj[(size_t)row * 64 + col] = acc2[rt][q] + b2;
            }
    }
}

__global__ void pool_kernel(const float* __restrict__ obj, const int* __restrict__ batch,
                            float* __restrict__ pooled, int n_obj)
{
    int i = blockIdx.x * 256 + threadIdx.x;
    int row = i >> 4, q = i & 15;
    if (row < n_obj) {
        float4 v = ((const float4*)obj)[(size_t)row * 16 + q];
        int g = batch[row];
        float* p = pooled + g * 64 + 4 * q;
        atomicAdd(p + 0, v.x);
        atomicAdd(p + 1, v.y);
        atomicAdd(p + 2, v.z);
        atomicAdd(p + 3, v.w);
    }
}

__launch_bounds__(128)
__global__ void readout_kernel(const float* __restrict__ pooled,
                               const float* __restrict__ w1, const float* __restrict__ b1,
                               const float* __restrict__ w2, const float* __restrict__ b2,
                               float* __restrict__ out)
{
    int g = blockIdx.x, c = threadIdx.x;
    __shared__ float xs[64];
    __shared__ float red[2];
    if (c < 64) xs[c] = pooled[g * 64 + c];
    __syncthreads();
    float h = b1[c];
#pragma unroll
    for (int k = 0; k < 64; ++k) h = fmaf(xs[k], w1[k * 128 + c], h);
    float v = fmaxf(h, 0.f) * w2[c];
#pragma unroll
    for (int off = 32; off > 0; off >>= 1) v += __shfl_down(v, off);
    if ((c & 63) == 0) red[c >> 6] = v;
    __syncthreads();
    if (c == 0) out[g] = red[0] + red[1] + b2[0];
}

extern "C" void kernel_launch(void* const* d_in, const int* in_sizes, int n_in,
                              void* d_out, int out_size, void* d_ws, size_t ws_size,
                              hipStream_t stream)
{
    const float* w_p1_1 = (const float*)d_in[4];
    const float* b_p1_1 = (const float*)d_in[5];
    const float* w_p1_2 = (const float*)d_in[6];
    const float* b_p1_2 = (const float*)d_in[7];
    const float* w_p2_1 = (const float*)d_in[8];
    const float* b_p2_1 = (const float*)d_in[9];
    const float* w_p2_2 = (const float*)d_in[10];
    const float* b_p2_2 = (const float*)d_in[11];
    const float* w_p3_1 = (const float*)d_in[12];
    const float* b_p3_1 = (const float*)d_in[13];
    const float* w_p3_2 = (const float*)d_in[14];
    const float* b_p3_2 = (const float*)d_in[15];
    const float* w_u1 = (const float*)d_in[16];
    const float* b_u1 = (const float*)d_in[17];
    const float* w_u2 = (const float*)d_in[18];
    const float* b_u2 = (const float*)d_in[19];
    const float* w_r1 = (const float*)d_in[20];
    const float* b_r1 = (const float*)d_in[21];
    const float* w_r2 = (const float*)d_in[22];
    const float* b_r2 = (const float*)d_in[23];
    const int* ei_p1 = (const int*)d_in[24];
    const int* ei_p2 = (const int*)d_in[25];
    const int* ei_p3 = (const int*)d_in[26];
    const int* batch = (const int*)d_in[27];

    const int n_obj = in_sizes[0];
    const int n_p1 = in_sizes[24];
    const int n_p2 = in_sizes[25] / 2;
    const int n_p3 = in_sizes[26] / 3;

    float* obj = (float*)d_ws;
    float* agg = obj + (size_t)n_obj * 64;
    float* pooled = agg + (size_t)n_obj * 64;
    _Float16* hb = (_Float16*)(pooled + (size_t)out_size * 64);
    // hi/lo plane offsets (halfs): see wprep
    const _Float16 *p1_1h = hb + 0,      *p1_1l = hb + 4096;
    const _Float16 *p1_2h = hb + 8192,   *p1_2l = hb + 12288;
    const _Float16 *p2_1h = hb + 16384,  *p2_1l = hb + 32768;
    const _Float16 *p2_2h = hb + 49152,  *p2_2l = hb + 65536;
    const _Float16 *p3_1h = hb + 81920,  *p3_1l = hb + 118784;
    const _Float16 *p3_2h = hb + 155648, *p3_2l = hb + 192512;
    const _Float16 *u1h   = hb + 229376, *u1l   = hb + 245760;
    const _Float16 *u2h   = hb + 262144, *u2l   = hb + 270336;

    wprep<<<544, 256, 0, stream>>>(w_p1_1, w_p1_2, w_p2_1, w_p2_2, w_p3_1, w_p3_2,
                                   w_u1, w_u2, hb);
    hipMemsetAsync(obj, 0, (size_t)n_obj * 64 * sizeof(float), stream);
    for (int l = 0; l < 3; ++l) {
        hipMemsetAsync(agg, 0, (size_t)n_obj * 64 * sizeof(float), stream);
        pred_mfma<1><<<(n_p1 + 63) / 64, 256, 0, stream>>>(
            obj, ei_p1, p1_1h, p1_1l, b_p1_1, p1_2h, p1_2l, b_p1_2, agg, n_p1);
        pred_mfma<2><<<(n_p2 + 63) / 64, 256, 0, stream>>>(
            obj, ei_p2, p2_1h, p2_1l, b_p2_1, p2_2h, p2_2l, b_p2_2, agg, n_p2);
        pred_mfma<3><<<(n_p3 + 63) / 64, 256, 0, stream>>>(
            obj, ei_p3, p3_1h, p3_1l, b_p3_1, p3_2h, p3_2l, b_p3_2, agg, n_p3);
        update_mfma<<<(n_obj + 63) / 64, 256, 0, stream>>>(
            obj, agg, u1h, u1l, b_u1, u2h, u2l, b_u2, n_obj);
    }
    hipMemsetAsync(pooled, 0, (size_t)out_size * 64 * sizeof(float), stream);
    pool_kernel<<<((size_t)n_obj * 16 + 255) / 256, 256, 0, stream>>>(obj, batch, pooled, n_obj);
    readout_kernel<<<out_size, 128, 0, stream>>>(pooled, w_r1, b_r1, w_r2, b_r2, (float*)d_out);
}

// Round 5
// 1412.897 us; speedup vs baseline: 7.7578x; 1.5054x over previous
//
#include <hip/hip_runtime.h>

typedef _Float16 h8 __attribute__((ext_vector_type(8)));
typedef _Float16 h4 __attribute__((ext_vector_type(4)));
typedef float f32x4 __attribute__((ext_vector_type(4)));

// 3-term split-product MFMA: A*B ~= AhBh + AhBl + AlBh (drop AlBl ~ 2^-22 rel)
__device__ __forceinline__ f32x4 mfma3(h8 ah, h8 al, h8 bh, h8 bl, f32x4 c) {
    c = __builtin_amdgcn_mfma_f32_16x16x32_f16(ah, bh, c, 0, 0, 0);
    c = __builtin_amdgcn_mfma_f32_16x16x32_f16(ah, bl, c, 0, 0, 0);
    c = __builtin_amdgcn_mfma_f32_16x16x32_f16(al, bh, c, 0, 0, 0);
    return c;
}

// ---- weight prep: for W[K][N] row-major, store hi/lo fp16 planes n-major ----
__launch_bounds__(256)
__global__ void wprep(const float* __restrict__ w_p1_1, const float* __restrict__ w_p1_2,
                      const float* __restrict__ w_p2_1, const float* __restrict__ w_p2_2,
                      const float* __restrict__ w_p3_1, const float* __restrict__ w_p3_2,
                      const float* __restrict__ w_u1, const float* __restrict__ w_u2,
                      _Float16* __restrict__ hb)
{
    int b = blockIdx.x;
    const float* src; int K, N, base; size_t off;
    if      (b < 16)  { src = w_p1_1; K = 64;  N = 64;  base = 0;   off = 0;      }
    else if (b < 32)  { src = w_p1_2; K = 64;  N = 64;  base = 16;  off = 8192;   }
    else if (b < 96)  { src = w_p2_1; K = 128; N = 128; base = 32;  off = 16384;  }
    else if (b < 160) { src = w_p2_2; K = 128; N = 128; base = 96;  off = 49152;  }
    else if (b < 304) { src = w_p3_1; K = 192; N = 192; base = 160; off = 81920;  }
    else if (b < 448) { src = w_p3_2; K = 192; N = 192; base = 304; off = 155648; }
    else if (b < 512) { src = w_u1;   K = 128; N = 128; base = 448; off = 229376; }
    else              { src = w_u2;   K = 128; N = 64;  base = 512; off = 262144; }
    int e = (b - base) * 256 + threadIdx.x;
    if (e < K * N) {
        int n = e / K, k = e - n * K;
        float x = src[k * N + n];
        _Float16 h = (_Float16)x;
        hb[off + e] = h;
        hb[off + (size_t)K * N + e] = (_Float16)(x - (float)h);
    }
}

// ---- layer-0 constant atom embeddings: a_const = b2 + relu(b1) @ W2 (fp32 exact) ----
__launch_bounds__(256)
__global__ void aconst_k(const float* __restrict__ b_p1_1, const float* __restrict__ w_p1_2,
                         const float* __restrict__ b_p1_2,
                         const float* __restrict__ b_p2_1, const float* __restrict__ w_p2_2,
                         const float* __restrict__ b_p2_2,
                         const float* __restrict__ b_p3_1, const float* __restrict__ w_p3_2,
                         const float* __restrict__ b_p3_2,
                         float* __restrict__ ac)   // [0:64)=p1, [64:192)=p2, [192:384)=p3
{
    int p = blockIdx.x;
    const float *b1, *w2, *b2; int D, off;
    if      (p == 0) { b1 = b_p1_1; w2 = w_p1_2; b2 = b_p1_2; D = 64;  off = 0;   }
    else if (p == 1) { b1 = b_p2_1; w2 = w_p2_2; b2 = b_p2_2; D = 128; off = 64;  }
    else             { b1 = b_p3_1; w2 = w_p3_2; b2 = b_p3_2; D = 192; off = 192; }
    int n = threadIdx.x;
    if (n < D) {
        float s = b2[n];
        for (int k = 0; k < D; ++k) {
            float h = b1[k];
            h = h > 0.f ? h : 0.f;
            s = fmaf(h, w2[k * D + n], s);
        }
        ac[off + n] = s;
    }
}

// ---- per-(pred,slot) degree histogram: 6 rows of n_obj counts ----
__launch_bounds__(256)
__global__ void hist_k(const int* __restrict__ ei1, const int* __restrict__ ei2,
                       const int* __restrict__ ei3, int* __restrict__ counts,
                       int n_obj, int n1, int n2, int n3)
{
    int e = blockIdx.x * 256 + threadIdx.x;
    int t1 = n1, t2 = n1 + 2 * n2, t3 = t2 + 3 * n3;
    if (e < t1) {
        atomicAdd(&counts[ei1[e]], 1);
    } else if (e < t2) {
        int x = e - t1; int slot = x / n2;
        atomicAdd(&counts[(size_t)(1 + slot) * n_obj + ei2[x]], 1);
    } else if (e < t3) {
        int x = e - t2; int slot = x / n3;
        atomicAdd(&counts[(size_t)(3 + slot) * n_obj + ei3[x]], 1);
    }
}

// ---- layer-0 agg = sum_j counts[j][o] * chunk[j][:]  (full overwrite) ----
__launch_bounds__(256)
__global__ void bcast_k(const int* __restrict__ counts, const float* __restrict__ ac,
                        float* __restrict__ agg, int n_obj)
{
    __shared__ float ch[384];
    int tid = threadIdx.x;
    for (int i = tid; i < 384; i += 256) ch[i] = ac[i];
    __syncthreads();
    int i = blockIdx.x * 256 + tid;
    int o = i >> 4, q = i & 15;
    if (o < n_obj) {
        float c[6];
#pragma unroll
        for (int j = 0; j < 6; ++j) c[j] = (float)counts[(size_t)j * n_obj + o];
        float4 v;
        float* vp = (float*)&v;
#pragma unroll
        for (int comp = 0; comp < 4; ++comp) {
            int col = 4 * q + comp;
            float s = 0.f;
#pragma unroll
            for (int j = 0; j < 6; ++j) s = fmaf(c[j], ch[j * 64 + col], s);
            vp[comp] = s;
        }
        ((float4*)agg)[(size_t)o * 16 + q] = v;
    }
}

// ---- fused pred body (device fn, dynamic LDS) ----
template<int R>
__device__ __forceinline__ void pred_body(
    char* smem,
    const float* __restrict__ obj, const int* __restrict__ ei,
    const _Float16* __restrict__ W1h, const _Float16* __restrict__ W1l,
    const float* __restrict__ B1,
    const _Float16* __restrict__ W2h, const _Float16* __restrict__ W2l,
    const float* __restrict__ B2,
    float* __restrict__ agg, int n_atoms, int blk)
{
    constexpr int D = 64 * R;
    constexpr int KC = D / 32;
    constexpr int LDA = D + 8;
    _Float16* Ah = (_Float16*)smem;
    _Float16* Al = Ah + 64 * LDA;
    int* eis = (int*)(Al + 64 * LDA);

    const int tid = threadIdx.x;
    const int wave = tid >> 6, lane = tid & 63;
    const int r = lane & 15, g = lane >> 4;
    const int a_base = blk * 64;
    const int tb = wave * R;

    for (int i = tid; i < R * 64; i += 256) {
        int s = i >> 6, a = i & 63;
        int ag = a_base + a; if (ag >= n_atoms) ag = n_atoms - 1;
        eis[i] = ei[s * n_atoms + ag];
    }
    __syncthreads();
    // gather: issue all loads first, then convert/store
    {
        const float4* obj4 = (const float4*)obj;
        float4 vv[4 * R];
#pragma unroll
        for (int i = 0; i < 4 * R; ++i) {
            int f = tid + 256 * i;
            int a = f / (R * 16), rem = f % (R * 16);
            int s = rem >> 4, q = rem & 15;
            vv[i] = obj4[(size_t)eis[s * 64 + a] * 16 + q];
        }
#pragma unroll
        for (int i = 0; i < 4 * R; ++i) {
            int f = tid + 256 * i;
            int a = f / (R * 16), rem = f % (R * 16);
            int s = rem >> 4, q = rem & 15;
            float4 v = vv[i];
            _Float16 h0 = (_Float16)v.x, h1 = (_Float16)v.y,
                     h2 = (_Float16)v.z, h3 = (_Float16)v.w;
            h4 hv = {h0, h1, h2, h3};
            h4 lv = {(_Float16)(v.x - (float)h0), (_Float16)(v.y - (float)h1),
                     (_Float16)(v.z - (float)h2), (_Float16)(v.w - (float)h3)};
            *(h4*)(Ah + a * LDA + s * 64 + 4 * q) = hv;
            *(h4*)(Al + a * LDA + s * 64 + 4 * q) = lv;
        }
    }
    __syncthreads();

    f32x4 z = {0.f, 0.f, 0.f, 0.f};
    f32x4 acc[4][R];
#pragma unroll
    for (int rt = 0; rt < 4; ++rt)
#pragma unroll
        for (int t = 0; t < R; ++t) acc[rt][t] = z;

    // ---- GEMM1 with double-buffered B prefetch ----
    {
        h8 bh[2][R], bl[2][R];
#pragma unroll
        for (int t = 0; t < R; ++t) {
            size_t wo = (size_t)((tb + t) * 16 + r) * D + g * 8;
            bh[0][t] = *(const h8*)(W1h + wo);
            bl[0][t] = *(const h8*)(W1l + wo);
        }
#pragma unroll
        for (int kc = 0; kc < KC; ++kc) {
            const int cur = kc & 1, nxt = cur ^ 1;
            if (kc + 1 < KC) {
#pragma unroll
                for (int t = 0; t < R; ++t) {
                    size_t wo = (size_t)((tb + t) * 16 + r) * D + (kc + 1) * 32 + g * 8;
                    bh[nxt][t] = *(const h8*)(W1h + wo);
                    bl[nxt][t] = *(const h8*)(W1l + wo);
                }
            }
            const int ko = kc * 32 + g * 8;
            h8 ah[4], al[4];
#pragma unroll
            for (int rt = 0; rt < 4; ++rt) {
                ah[rt] = *(const h8*)(Ah + (rt * 16 + r) * LDA + ko);
                al[rt] = *(const h8*)(Al + (rt * 16 + r) * LDA + ko);
            }
#pragma unroll
            for (int t = 0; t < R; ++t)
#pragma unroll
                for (int rt = 0; rt < 4; ++rt)
                    acc[rt][t] = mfma3(ah[rt], al[rt], bh[cur][t], bl[cur][t], acc[rt][t]);
        }
    }
    __syncthreads();

    // ---- epilogue 1: relu(acc+b1) -> Ah/Al ----
#pragma unroll
    for (int t = 0; t < R; ++t) {
        int col = (tb + t) * 16 + r;
        float b1 = B1[col];
#pragma unroll
        for (int rt = 0; rt < 4; ++rt)
#pragma unroll
            for (int q = 0; q < 4; ++q) {
                int row = rt * 16 + g * 4 + q;
                float h = acc[rt][t][q] + b1;
                h = h > 0.f ? h : 0.f;
                _Float16 hh = (_Float16)h;
                Ah[row * LDA + col] = hh;
                Al[row * LDA + col] = (_Float16)(h - (float)hh);
            }
    }
    __syncthreads();

    // ---- GEMM2 ----
#pragma unroll
    for (int rt = 0; rt < 4; ++rt)
#pragma unroll
        for (int t = 0; t < R; ++t) acc[rt][t] = z;
    {
        h8 bh[2][R], bl[2][R];
#pragma unroll
        for (int t = 0; t < R; ++t) {
            size_t wo = (size_t)((tb + t) * 16 + r) * D + g * 8;
            bh[0][t] = *(const h8*)(W2h + wo);
            bl[0][t] = *(const h8*)(W2l + wo);
        }
#pragma unroll
        for (int kc = 0; kc < KC; ++kc) {
            const int cur = kc & 1, nxt = cur ^ 1;
            if (kc + 1 < KC) {
#pragma unroll
                for (int t = 0; t < R; ++t) {
                    size_t wo = (size_t)((tb + t) * 16 + r) * D + (kc + 1) * 32 + g * 8;
                    bh[nxt][t] = *(const h8*)(W2h + wo);
                    bl[nxt][t] = *(const h8*)(W2l + wo);
                }
            }
            const int ko = kc * 32 + g * 8;
            h8 ah[4], al[4];
#pragma unroll
            for (int rt = 0; rt < 4; ++rt) {
                ah[rt] = *(const h8*)(Ah + (rt * 16 + r) * LDA + ko);
                al[rt] = *(const h8*)(Al + (rt * 16 + r) * LDA + ko);
            }
#pragma unroll
            for (int t = 0; t < R; ++t)
#pragma unroll
                for (int rt = 0; rt < 4; ++rt)
                    acc[rt][t] = mfma3(ah[rt], al[rt], bh[cur][t], bl[cur][t], acc[rt][t]);
        }
    }

    // ---- scatter ----
#pragma unroll
    for (int t = 0; t < R; ++t) {
        int col = (tb + t) * 16 + r;
        float b2 = B2[col];
        int s = col >> 6, cc = col & 63;
#pragma unroll
        for (int rt = 0; rt < 4; ++rt)
#pragma unroll
            for (int q = 0; q < 4; ++q) {
                int row = rt * 16 + g * 4 + q;
                int atom = a_base + row;
                if (atom < n_atoms)
                    atomicAdd(agg + (size_t)eis[s * 64 + row] * 64 + cc,
                              acc[rt][t][q] + b2);
            }
    }
}

// ---- single fused launch for all three predicates ----
__launch_bounds__(256, 3)
__global__ void pred_all(const float* __restrict__ obj, float* __restrict__ agg,
                         const int* __restrict__ ei1, const int* __restrict__ ei2,
                         const int* __restrict__ ei3,
                         const _Float16* __restrict__ hb,
                         const float* __restrict__ b_p1_1, const float* __restrict__ b_p1_2,
                         const float* __restrict__ b_p2_1, const float* __restrict__ b_p2_2,
                         const float* __restrict__ b_p3_1, const float* __restrict__ b_p3_2,
                         int n1, int n2, int n3, int nb3, int nb2)
{
    extern __shared__ char smem[];
    int b = blockIdx.x;
    if (b < nb3) {
        pred_body<3>(smem, obj, ei3, hb + 81920, hb + 118784, b_p3_1,
                     hb + 155648, hb + 192512, b_p3_2, agg, n3, b);
    } else if (b < nb3 + nb2) {
        pred_body<2>(smem, obj, ei2, hb + 16384, hb + 32768, b_p2_1,
                     hb + 49152, hb + 65536, b_p2_2, agg, n2, b - nb3);
    } else {
        pred_body<1>(smem, obj, ei1, hb + 0, hb + 4096, b_p1_1,
                     hb + 8192, hb + 12288, b_p1_2, agg, n1, b - nb3 - nb2);
    }
}

// ---- obj update: obj = MLP_u([obj|agg]) 128->128(relu)->64; FIRST treats obj as 0 ----
template<int FIRST>
__launch_bounds__(256, 4)
__global__ void update_mfma(float* __restrict__ obj, float* __restrict__ agg,
                            const _Float16* __restrict__ W1h, const _Float16* __restrict__ W1l,
                            const float* __restrict__ B1,
                            const _Float16* __restrict__ W2h, const _Float16* __restrict__ W2l,
                            const float* __restrict__ B2,
                            int n_obj, int zero_agg)
{
    constexpr int LDA = 136;
    __shared__ _Float16 Ah[64 * LDA];
    __shared__ _Float16 Al[64 * LDA];

    const int tid = threadIdx.x;
    const int wave = tid >> 6, lane = tid & 63;
    const int r = lane & 15, g = lane >> 4;
    const int a_base = blockIdx.x * 64;

    {
        const float4* o4 = (const float4*)obj;
        const float4* g4 = (const float4*)agg;
#pragma unroll
        for (int i = 0; i < 8; ++i) {
            int f = tid + 256 * i;
            int a = f >> 5, q = f & 31;
            int rg = a_base + a; if (rg >= n_obj) rg = n_obj - 1;
            float4 v;
            if (FIRST && q < 16) {
                v = make_float4(0.f, 0.f, 0.f, 0.f);
            } else {
                v = (q < 16) ? o4[(size_t)rg * 16 + q] : g4[(size_t)rg * 16 + (q - 16)];
            }
            _Float16 h0 = (_Float16)v.x, h1 = (_Float16)v.y,
                     h2 = (_Float16)v.z, h3 = (_Float16)v.w;
            h4 hv = {h0, h1, h2, h3};
            h4 lv = {(_Float16)(v.x - (float)h0), (_Float16)(v.y - (float)h1),
                     (_Float16)(v.z - (float)h2), (_Float16)(v.w - (float)h3)};
            *(h4*)(Ah + a * LDA + 4 * q) = hv;
            *(h4*)(Al + a * LDA + 4 * q) = lv;
        }
    }
    __syncthreads();

    f32x4 z = {0.f, 0.f, 0.f, 0.f};
    f32x4 acc[4][2];
#pragma unroll
    for (int rt = 0; rt < 4; ++rt) { acc[rt][0] = z; acc[rt][1] = z; }
    {
        h8 bh[2][2], bl[2][2];
#pragma unroll
        for (int t = 0; t < 2; ++t) {
            size_t wo = (size_t)((wave * 2 + t) * 16 + r) * 128 + g * 8;
            bh[0][t] = *(const h8*)(W1h + wo);
            bl[0][t] = *(const h8*)(W1l + wo);
        }
#pragma unroll
        for (int kc = 0; kc < 4; ++kc) {
            const int cur = kc & 1, nxt = cur ^ 1;
            if (kc + 1 < 4) {
#pragma unroll
                for (int t = 0; t < 2; ++t) {
                    size_t wo = (size_t)((wave * 2 + t) * 16 + r) * 128 + (kc + 1) * 32 + g * 8;
                    bh[nxt][t] = *(const h8*)(W1h + wo);
                    bl[nxt][t] = *(const h8*)(W1l + wo);
                }
            }
            const int ko = kc * 32 + g * 8;
            h8 ah[4], al[4];
#pragma unroll
            for (int rt = 0; rt < 4; ++rt) {
                ah[rt] = *(const h8*)(Ah + (rt * 16 + r) * LDA + ko);
                al[rt] = *(const h8*)(Al + (rt * 16 + r) * LDA + ko);
            }
#pragma unroll
            for (int t = 0; t < 2; ++t)
#pragma unroll
                for (int rt = 0; rt < 4; ++rt)
                    acc[rt][t] = mfma3(ah[rt], al[rt], bh[cur][t], bl[cur][t], acc[rt][t]);
        }
    }
    __syncthreads();
#pragma unroll
    for (int t = 0; t < 2; ++t) {
        int col = (wave * 2 + t) * 16 + r;
        float b1 = B1[col];
#pragma unroll
        for (int rt = 0; rt < 4; ++rt)
#pragma unroll
            for (int q = 0; q < 4; ++q) {
                int row = rt * 16 + g * 4 + q;
                float h = acc[rt][t][q] + b1;
                h = h > 0.f ? h : 0.f;
                _Float16 hh = (_Float16)h;
                Ah[row * LDA + col] = hh;
                Al[row * LDA + col] = (_Float16)(h - (float)hh);
            }
    }
    __syncthreads();

    f32x4 acc2[4];
#pragma unroll
    for (int rt = 0; rt < 4; ++rt) acc2[rt] = z;
    {
        h8 bh[2], bl[2];
        {
            size_t wo = (size_t)(wave * 16 + r) * 128 + g * 8;
            bh[0] = *(const h8*)(W2h + wo);
            bl[0] = *(const h8*)(W2l + wo);
        }
#pragma unroll
        for (int kc = 0; kc < 4; ++kc) {
            const int cur = kc & 1, nxt = cur ^ 1;
            if (kc + 1 < 4) {
                size_t wo = (size_t)(wave * 16 + r) * 128 + (kc + 1) * 32 + g * 8;
                bh[nxt] = *(const h8*)(W2h + wo);
                bl[nxt] = *(const h8*)(W2l + wo);
            }
            const int ko = kc * 32 + g * 8;
#pragma unroll
            for (int rt = 0; rt < 4; ++rt) {
                h8 ah = *(const h8*)(Ah + (rt * 16 + r) * LDA + ko);
                h8 al = *(const h8*)(Al + (rt * 16 + r) * LDA + ko);
                acc2[rt] = mfma3(ah, al, bh[cur], bl[cur], acc2[rt]);
            }
        }
    }
    {
        int col = wave * 16 + r;
        float b2 = B2[col];
#pragma unroll
        for (int rt = 0; rt < 4; ++rt)
#pragma unroll
            for (int q = 0; q < 4; ++q) {
                int row = a_base + rt * 16 + g * 4 + q;
                if (row < n_obj)
                    obj[(size_t)row * 64 + col] = acc2[rt][q] + b2;
            }
    }
    if (zero_agg) {
        float4 zz = make_float4(0.f, 0.f, 0.f, 0.f);
#pragma unroll
        for (int i = 0; i < 4; ++i) {
            int f = tid + 256 * i;
            int a = f >> 4, q = f & 15;
            int rg = a_base + a;
            if (rg < n_obj) ((float4*)agg)[(size_t)rg * 16 + q] = zz;
        }
    }
}

__global__ void pool_kernel(const float* __restrict__ obj, const int* __restrict__ batch,
                            float* __restrict__ pooled, int n_obj)
{
    int i = blockIdx.x * 256 + threadIdx.x;
    int row = i >> 4, q = i & 15;
    if (row < n_obj) {
        float4 v = ((const float4*)obj)[(size_t)row * 16 + q];
        int g = batch[row];
        float* p = pooled + g * 64 + 4 * q;
        atomicAdd(p + 0, v.x);
        atomicAdd(p + 1, v.y);
        atomicAdd(p + 2, v.z);
        atomicAdd(p + 3, v.w);
    }
}

__launch_bounds__(128)
__global__ void readout_kernel(const float* __restrict__ pooled,
                               const float* __restrict__ w1, const float* __restrict__ b1,
                               const float* __restrict__ w2, const float* __restrict__ b2,
                               float* __restrict__ out)
{
    int g = blockIdx.x, c = threadIdx.x;
    __shared__ float xs[64];
    __shared__ float red[2];
    if (c < 64) xs[c] = pooled[g * 64 + c];
    __syncthreads();
    float h = b1[c];
#pragma unroll
    for (int k = 0; k < 64; ++k) h = fmaf(xs[k], w1[k * 128 + c], h);
    float v = fmaxf(h, 0.f) * w2[c];
#pragma unroll
    for (int off = 32; off > 0; off >>= 1) v += __shfl_down(v, off);
    if ((c & 63) == 0) red[c >> 6] = v;
    __syncthreads();
    if (c == 0) out[g] = red[0] + red[1] + b2[0];
}

extern "C" void kernel_launch(void* const* d_in, const int* in_sizes, int n_in,
                              void* d_out, int out_size, void* d_ws, size_t ws_size,
                              hipStream_t stream)
{
    const float* w_p1_1 = (const float*)d_in[4];
    const float* b_p1_1 = (const float*)d_in[5];
    const float* w_p1_2 = (const float*)d_in[6];
    const float* b_p1_2 = (const float*)d_in[7];
    const float* w_p2_1 = (const float*)d_in[8];
    const float* b_p2_1 = (const float*)d_in[9];
    const float* w_p2_2 = (const float*)d_in[10];
    const float* b_p2_2 = (const float*)d_in[11];
    const float* w_p3_1 = (const float*)d_in[12];
    const float* b_p3_1 = (const float*)d_in[13];
    const float* w_p3_2 = (const float*)d_in[14];
    const float* b_p3_2 = (const float*)d_in[15];
    const float* w_u1 = (const float*)d_in[16];
    const float* b_u1 = (const float*)d_in[17];
    const float* w_u2 = (const float*)d_in[18];
    const float* b_u2 = (const float*)d_in[19];
    const float* w_r1 = (const float*)d_in[20];
    const float* b_r1 = (const float*)d_in[21];
    const float* w_r2 = (const float*)d_in[22];
    const float* b_r2 = (const float*)d_in[23];
    const int* ei_p1 = (const int*)d_in[24];
    const int* ei_p2 = (const int*)d_in[25];
    const int* ei_p3 = (const int*)d_in[26];
    const int* batch = (const int*)d_in[27];

    const int n_obj = in_sizes[0];
    const int n_p1 = in_sizes[24];
    const int n_p2 = in_sizes[25] / 2;
    const int n_p3 = in_sizes[26] / 3;

    float* obj = (float*)d_ws;
    float* agg = obj + (size_t)n_obj * 64;
    float* pooled = agg + (size_t)n_obj * 64;
    _Float16* hb = (_Float16*)(pooled + (size_t)out_size * 64);
    float* endf = (float*)(hb + 278528);
    // counts + aconst alias the obj region (consumed by bcast_k before obj is written)
    int* counts = (int*)obj;
    float* ac = (float*)(counts + 6 * (size_t)n_obj);

    const int nb3 = (n_p3 + 63) / 64, nb2 = (n_p2 + 63) / 64, nb1 = (n_p1 + 63) / 64;
    const int pred_smem = 2 * 64 * (192 + 8) * 2 + 3 * 64 * 4;  // 51968 B
    (void)endf; (void)ws_size;

    wprep<<<544, 256, 0, stream>>>(w_p1_1, w_p1_2, w_p2_1, w_p2_2, w_p3_1, w_p3_2,
                                   w_u1, w_u2, hb);
    aconst_k<<<3, 256, 0, stream>>>(b_p1_1, w_p1_2, b_p1_2, b_p2_1, w_p2_2, b_p2_2,
                                    b_p3_1, w_p3_2, b_p3_2, ac);
    hipMemsetAsync(counts, 0, 6 * (size_t)n_obj * sizeof(int), stream);
    {
        int tot = n_p1 + 2 * n_p2 + 3 * n_p3;
        hist_k<<<(tot + 255) / 256, 256, 0, stream>>>(ei_p1, ei_p2, ei_p3, counts,
                                                      n_obj, n_p1, n_p2, n_p3);
    }
    bcast_k<<<((size_t)n_obj * 16 + 255) / 256, 256, 0, stream>>>(counts, ac, agg, n_obj);
    // layer 0 update (obj treated as zeros), zero agg for layer 1
    update_mfma<1><<<(n_obj + 63) / 64, 256, 0, stream>>>(
        obj, agg, hb + 229376, hb + 245760, b_u1, hb + 262144, hb + 270336, b_u2,
        n_obj, 1);
    for (int l = 1; l < 3; ++l) {
        pred_all<<<nb3 + nb2 + nb1, 256, pred_smem, stream>>>(
            obj, agg, ei_p1, ei_p2, ei_p3, hb,
            b_p1_1, b_p1_2, b_p2_1, b_p2_2, b_p3_1, b_p3_2,
            n_p1, n_p2, n_p3, nb3, nb2);
        update_mfma<0><<<(n_obj + 63) / 64, 256, 0, stream>>>(
            obj, agg, hb + 229376, hb + 245760, b_u1, hb + 262144, hb + 270336, b_u2,
            n_obj, l < 2 ? 1 : 0);
    }
    hipMemsetAsync(pooled, 0, (size_t)out_size * 64 * sizeof(float), stream);
    pool_kernel<<<((size_t)n_obj * 16 + 255) / 256, 256, 0, stream>>>(obj, batch, pooled, n_obj);
    readout_kernel<<<out_size, 128, 0, stream>>>(pooled, w_r1, b_r1, w_r2, b_r2, (float*)d_out);
}

// Round 6
// 1326.138 us; speedup vs baseline: 8.2653x; 1.0654x over previous
//
#include <hip/hip_runtime.h>

typedef _Float16 h8 __attribute__((ext_vector_type(8)));
typedef _Float16 h4 __attribute__((ext_vector_type(4)));
typedef float f32x4 __attribute__((ext_vector_type(4)));

// 2-term split-product MFMA: A*B ~= Ah·Bh + Ah·Bl  (A pre-rounded to fp16)
__device__ __forceinline__ f32x4 mfma2(h8 ah, h8 bh, h8 bl, f32x4 c) {
    c = __builtin_amdgcn_mfma_f32_16x16x32_f16(ah, bh, c, 0, 0, 0);
    c = __builtin_amdgcn_mfma_f32_16x16x32_f16(ah, bl, c, 0, 0, 0);
    return c;
}

// ---- weight prep: for W[K][N] row-major, store hi/lo fp16 planes n-major ----
__launch_bounds__(256)
__global__ void wprep(const float* __restrict__ w_p1_1, const float* __restrict__ w_p1_2,
                      const float* __restrict__ w_p2_1, const float* __restrict__ w_p2_2,
                      const float* __restrict__ w_p3_1, const float* __restrict__ w_p3_2,
                      const float* __restrict__ w_u1, const float* __restrict__ w_u2,
                      _Float16* __restrict__ hb)
{
    int b = blockIdx.x;
    const float* src; int K, N, base; size_t off;
    if      (b < 16)  { src = w_p1_1; K = 64;  N = 64;  base = 0;   off = 0;      }
    else if (b < 32)  { src = w_p1_2; K = 64;  N = 64;  base = 16;  off = 8192;   }
    else if (b < 96)  { src = w_p2_1; K = 128; N = 128; base = 32;  off = 16384;  }
    else if (b < 160) { src = w_p2_2; K = 128; N = 128; base = 96;  off = 49152;  }
    else if (b < 304) { src = w_p3_1; K = 192; N = 192; base = 160; off = 81920;  }
    else if (b < 448) { src = w_p3_2; K = 192; N = 192; base = 304; off = 155648; }
    else if (b < 512) { src = w_u1;   K = 128; N = 128; base = 448; off = 229376; }
    else              { src = w_u2;   K = 128; N = 64;  base = 512; off = 262144; }
    int e = (b - base) * 256 + threadIdx.x;
    if (e < K * N) {
        int n = e / K, k = e - n * K;
        float x = src[k * N + n];
        _Float16 h = (_Float16)x;
        hb[off + e] = h;
        hb[off + (size_t)K * N + e] = (_Float16)(x - (float)h);
    }
}

// ---- layer-0 constant atom embeddings: a_const = b2 + relu(b1) @ W2 (fp32 exact) ----
__launch_bounds__(256)
__global__ void aconst_k(const float* __restrict__ b_p1_1, const float* __restrict__ w_p1_2,
                         const float* __restrict__ b_p1_2,
                         const float* __restrict__ b_p2_1, const float* __restrict__ w_p2_2,
                         const float* __restrict__ b_p2_2,
                         const float* __restrict__ b_p3_1, const float* __restrict__ w_p3_2,
                         const float* __restrict__ b_p3_2,
                         float* __restrict__ ac)   // [0:64)=p1, [64:192)=p2, [192:384)=p3
{
    int p = blockIdx.x;
    const float *b1, *w2, *b2; int D, off;
    if      (p == 0) { b1 = b_p1_1; w2 = w_p1_2; b2 = b_p1_2; D = 64;  off = 0;   }
    else if (p == 1) { b1 = b_p2_1; w2 = w_p2_2; b2 = b_p2_2; D = 128; off = 64;  }
    else             { b1 = b_p3_1; w2 = w_p3_2; b2 = b_p3_2; D = 192; off = 192; }
    int n = threadIdx.x;
    if (n < D) {
        float s = b2[n];
        for (int k = 0; k < D; ++k) {
            float h = b1[k];
            h = h > 0.f ? h : 0.f;
            s = fmaf(h, w2[k * D + n], s);
        }
        ac[off + n] = s;
    }
}

// ---- per-(pred,slot) degree histogram: 6 rows of n_obj counts ----
__launch_bounds__(256)
__global__ void hist_k(const int* __restrict__ ei1, const int* __restrict__ ei2,
                       const int* __restrict__ ei3, int* __restrict__ counts,
                       int n_obj, int n1, int n2, int n3)
{
    int e = blockIdx.x * 256 + threadIdx.x;
    int t1 = n1, t2 = n1 + 2 * n2, t3 = t2 + 3 * n3;
    if (e < t1) {
        atomicAdd(&counts[ei1[e]], 1);
    } else if (e < t2) {
        int x = e - t1; int slot = x / n2;
        atomicAdd(&counts[(size_t)(1 + slot) * n_obj + ei2[x]], 1);
    } else if (e < t3) {
        int x = e - t2; int slot = x / n3;
        atomicAdd(&counts[(size_t)(3 + slot) * n_obj + ei3[x]], 1);
    }
}

// ---- layer-0 agg = sum_j counts[j][o] * chunk[j][:]  (full overwrite) ----
__launch_bounds__(256)
__global__ void bcast_k(const int* __restrict__ counts, const float* __restrict__ ac,
                        float* __restrict__ agg, int n_obj)
{
    __shared__ float ch[384];
    int tid = threadIdx.x;
    for (int i = tid; i < 384; i += 256) ch[i] = ac[i];
    __syncthreads();
    int i = blockIdx.x * 256 + tid;
    int o = i >> 4, q = i & 15;
    if (o < n_obj) {
        float c[6];
#pragma unroll
        for (int j = 0; j < 6; ++j) c[j] = (float)counts[(size_t)j * n_obj + o];
        float4 v;
        float* vp = (float*)&v;
#pragma unroll
        for (int comp = 0; comp < 4; ++comp) {
            int col = 4 * q + comp;
            float s = 0.f;
#pragma unroll
            for (int j = 0; j < 6; ++j) s = fmaf(c[j], ch[j * 64 + col], s);
            vp[comp] = s;
        }
        ((float4*)agg)[(size_t)o * 16 + q] = v;
    }
}

// ---- fused pred body (device fn, dynamic LDS), A single fp16 plane ----
template<int R>
__device__ __forceinline__ void pred_body(
    char* smem,
    const _Float16* __restrict__ objh, const int* __restrict__ ei,
    const _Float16* __restrict__ W1h, const _Float16* __restrict__ W1l,
    const float* __restrict__ B1,
    const _Float16* __restrict__ W2h, const _Float16* __restrict__ W2l,
    const float* __restrict__ B2,
    float* __restrict__ agg, int n_atoms, int blk)
{
    constexpr int D = 64 * R;
    constexpr int KC = D / 32;
    constexpr int LDA = D + 8;
    _Float16* Ah = (_Float16*)smem;
    int* eis = (int*)(Ah + 64 * LDA);

    const int tid = threadIdx.x;
    const int wave = tid >> 6, lane = tid & 63;
    const int r = lane & 15, g = lane >> 4;
    const int a_base = blk * 64;
    const int tb = wave * R;

    for (int i = tid; i < R * 64; i += 256) {
        int s = i >> 6, a = i & 63;
        int ag = a_base + a; if (ag >= n_atoms) ag = n_atoms - 1;
        eis[i] = ei[s * n_atoms + ag];
    }
    __syncthreads();
    // gather fp16 rows directly: Ah[a][s*64 + c*8 ..] = objh[eis[s][a]][c*8..]
    {
        h8 vv[2 * R];
#pragma unroll
        for (int i = 0; i < 2 * R; ++i) {
            int f = tid + 256 * i;
            int rowslot = f >> 3, c = f & 7;
            int s = rowslot >> 6, a = rowslot & 63;
            vv[i] = *(const h8*)(objh + (size_t)eis[s * 64 + a] * 64 + c * 8);
        }
#pragma unroll
        for (int i = 0; i < 2 * R; ++i) {
            int f = tid + 256 * i;
            int rowslot = f >> 3, c = f & 7;
            int s = rowslot >> 6, a = rowslot & 63;
            *(h8*)(Ah + a * LDA + s * 64 + c * 8) = vv[i];
        }
    }
    __syncthreads();

    f32x4 z = {0.f, 0.f, 0.f, 0.f};
    f32x4 acc[4][R];
#pragma unroll
    for (int rt = 0; rt < 4; ++rt)
#pragma unroll
        for (int t = 0; t < R; ++t) acc[rt][t] = z;

    // ---- GEMM1 with double-buffered B prefetch ----
    {
        h8 bh[2][R], bl[2][R];
#pragma unroll
        for (int t = 0; t < R; ++t) {
            size_t wo = (size_t)((tb + t) * 16 + r) * D + g * 8;
            bh[0][t] = *(const h8*)(W1h + wo);
            bl[0][t] = *(const h8*)(W1l + wo);
        }
#pragma unroll
        for (int kc = 0; kc < KC; ++kc) {
            const int cur = kc & 1, nxt = cur ^ 1;
            if (kc + 1 < KC) {
#pragma unroll
                for (int t = 0; t < R; ++t) {
                    size_t wo = (size_t)((tb + t) * 16 + r) * D + (kc + 1) * 32 + g * 8;
                    bh[nxt][t] = *(const h8*)(W1h + wo);
                    bl[nxt][t] = *(const h8*)(W1l + wo);
                }
            }
            const int ko = kc * 32 + g * 8;
            h8 ah[4];
#pragma unroll
            for (int rt = 0; rt < 4; ++rt)
                ah[rt] = *(const h8*)(Ah + (rt * 16 + r) * LDA + ko);
#pragma unroll
            for (int t = 0; t < R; ++t)
#pragma unroll
                for (int rt = 0; rt < 4; ++rt)
                    acc[rt][t] = mfma2(ah[rt], bh[cur][t], bl[cur][t], acc[rt][t]);
        }
    }
    __syncthreads();

    // ---- epilogue 1: fp16(relu(acc+b1)) -> Ah ----
#pragma unroll
    for (int t = 0; t < R; ++t) {
        int col = (tb + t) * 16 + r;
        float b1 = B1[col];
#pragma unroll
        for (int rt = 0; rt < 4; ++rt)
#pragma unroll
            for (int q = 0; q < 4; ++q) {
                int row = rt * 16 + g * 4 + q;
                float h = acc[rt][t][q] + b1;
                h = h > 0.f ? h : 0.f;
                Ah[row * LDA + col] = (_Float16)h;
            }
    }
    __syncthreads();

    // ---- GEMM2 ----
#pragma unroll
    for (int rt = 0; rt < 4; ++rt)
#pragma unroll
        for (int t = 0; t < R; ++t) acc[rt][t] = z;
    {
        h8 bh[2][R], bl[2][R];
#pragma unroll
        for (int t = 0; t < R; ++t) {
            size_t wo = (size_t)((tb + t) * 16 + r) * D + g * 8;
            bh[0][t] = *(const h8*)(W2h + wo);
            bl[0][t] = *(const h8*)(W2l + wo);
        }
#pragma unroll
        for (int kc = 0; kc < KC; ++kc) {
            const int cur = kc & 1, nxt = cur ^ 1;
            if (kc + 1 < KC) {
#pragma unroll
                for (int t = 0; t < R; ++t) {
                    size_t wo = (size_t)((tb + t) * 16 + r) * D + (kc + 1) * 32 + g * 8;
                    bh[nxt][t] = *(const h8*)(W2h + wo);
                    bl[nxt][t] = *(const h8*)(W2l + wo);
                }
            }
            const int ko = kc * 32 + g * 8;
            h8 ah[4];
#pragma unroll
            for (int rt = 0; rt < 4; ++rt)
                ah[rt] = *(const h8*)(Ah + (rt * 16 + r) * LDA + ko);
#pragma unroll
            for (int t = 0; t < R; ++t)
#pragma unroll
                for (int rt = 0; rt < 4; ++rt)
                    acc[rt][t] = mfma2(ah[rt], bh[cur][t], bl[cur][t], acc[rt][t]);
        }
    }

    // ---- scatter ----
#pragma unroll
    for (int t = 0; t < R; ++t) {
        int col = (tb + t) * 16 + r;
        float b2 = B2[col];
        int s = col >> 6, cc = col & 63;
#pragma unroll
        for (int rt = 0; rt < 4; ++rt)
#pragma unroll
            for (int q = 0; q < 4; ++q) {
                int row = rt * 16 + g * 4 + q;
                int atom = a_base + row;
                if (atom < n_atoms)
                    atomicAdd(agg + (size_t)eis[s * 64 + row] * 64 + cc,
                              acc[rt][t][q] + b2);
            }
    }
}

// ---- single fused launch for all three predicates ----
__launch_bounds__(256, 6)
__global__ void pred_all(const _Float16* __restrict__ objh, float* __restrict__ agg,
                         const int* __restrict__ ei1, const int* __restrict__ ei2,
                         const int* __restrict__ ei3,
                         const _Float16* __restrict__ hb,
                         const float* __restrict__ b_p1_1, const float* __restrict__ b_p1_2,
                         const float* __restrict__ b_p2_1, const float* __restrict__ b_p2_2,
                         const float* __restrict__ b_p3_1, const float* __restrict__ b_p3_2,
                         int n1, int n2, int n3, int nb3, int nb2)
{
    extern __shared__ char smem[];
    int b = blockIdx.x;
    if (b < nb3) {
        pred_body<3>(smem, objh, ei3, hb + 81920, hb + 118784, b_p3_1,
                     hb + 155648, hb + 192512, b_p3_2, agg, n3, b);
    } else if (b < nb3 + nb2) {
        pred_body<2>(smem, objh, ei2, hb + 16384, hb + 32768, b_p2_1,
                     hb + 49152, hb + 65536, b_p2_2, agg, n2, b - nb3);
    } else {
        pred_body<1>(smem, objh, ei1, hb + 0, hb + 4096, b_p1_1,
                     hb + 8192, hb + 12288, b_p1_2, agg, n1, b - nb3 - nb2);
    }
}

// ---- obj update: objh = fp16(MLP_u([obj|agg])); LAST also writes fp32 into agg ----
template<int FIRST>
__launch_bounds__(256, 4)
__global__ void update_mfma(_Float16* __restrict__ objh, float* __restrict__ agg,
                            const _Float16* __restrict__ W1h, const _Float16* __restrict__ W1l,
                            const float* __restrict__ B1,
                            const _Float16* __restrict__ W2h, const _Float16* __restrict__ W2l,
                            const float* __restrict__ B2,
                            int n_obj, int zero_agg, int last)
{
    constexpr int LDA = 136;
    __shared__ _Float16 Ah[64 * LDA];

    const int tid = threadIdx.x;
    const int wave = tid >> 6, lane = tid & 63;
    const int r = lane & 15, g = lane >> 4;
    const int a_base = blockIdx.x * 64;

    // A = [objh | fp16(agg)]  (64 rows x 128 cols, fp16)
    {
#pragma unroll
        for (int i = 0; i < 4; ++i) {
            int f = tid + 256 * i;
            int a = f >> 4, c = f & 15;
            int rg = a_base + a; if (rg >= n_obj) rg = n_obj - 1;
            h8 v;
            if (c < 8) {
                if (FIRST) {
                    v = (h8)(_Float16)0.f;
                } else {
                    v = *(const h8*)(objh + (size_t)rg * 64 + c * 8);
                }
            } else {
                float4 f0 = ((const float4*)agg)[(size_t)rg * 16 + (c - 8) * 2];
                float4 f1 = ((const float4*)agg)[(size_t)rg * 16 + (c - 8) * 2 + 1];
                v[0] = (_Float16)f0.x; v[1] = (_Float16)f0.y;
                v[2] = (_Float16)f0.z; v[3] = (_Float16)f0.w;
                v[4] = (_Float16)f1.x; v[5] = (_Float16)f1.y;
                v[6] = (_Float16)f1.z; v[7] = (_Float16)f1.w;
            }
            *(h8*)(Ah + a * LDA + c * 8) = v;
        }
    }
    __syncthreads();

    f32x4 z = {0.f, 0.f, 0.f, 0.f};
    f32x4 acc[4][2];
#pragma unroll
    for (int rt = 0; rt < 4; ++rt) { acc[rt][0] = z; acc[rt][1] = z; }
    {
        h8 bh[2][2], bl[2][2];
#pragma unroll
        for (int t = 0; t < 2; ++t) {
            size_t wo = (size_t)((wave * 2 + t) * 16 + r) * 128 + g * 8;
            bh[0][t] = *(const h8*)(W1h + wo);
            bl[0][t] = *(const h8*)(W1l + wo);
        }
#pragma unroll
        for (int kc = 0; kc < 4; ++kc) {
            const int cur = kc & 1, nxt = cur ^ 1;
            if (kc + 1 < 4) {
#pragma unroll
                for (int t = 0; t < 2; ++t) {
                    size_t wo = (size_t)((wave * 2 + t) * 16 + r) * 128 + (kc + 1) * 32 + g * 8;
                    bh[nxt][t] = *(const h8*)(W1h + wo);
                    bl[nxt][t] = *(const h8*)(W1l + wo);
                }
            }
            const int ko = kc * 32 + g * 8;
            h8 ah[4];
#pragma unroll
            for (int rt = 0; rt < 4; ++rt)
                ah[rt] = *(const h8*)(Ah + (rt * 16 + r) * LDA + ko);
#pragma unroll
            for (int t = 0; t < 2; ++t)
#pragma unroll
                for (int rt = 0; rt < 4; ++rt)
                    acc[rt][t] = mfma2(ah[rt], bh[cur][t], bl[cur][t], acc[rt][t]);
        }
    }
    __syncthreads();
#pragma unroll
    for (int t = 0; t < 2; ++t) {
        int col = (wave * 2 + t) * 16 + r;
        float b1 = B1[col];
#pragma unroll
        for (int rt = 0; rt < 4; ++rt)
#pragma unroll
            for (int q = 0; q < 4; ++q) {
                int row = rt * 16 + g * 4 + q;
                float h = acc[rt][t][q] + b1;
                h = h > 0.f ? h : 0.f;
                Ah[row * LDA + col] = (_Float16)h;
            }
    }
    __syncthreads();

    f32x4 acc2[4];
#pragma unroll
    for (int rt = 0; rt < 4; ++rt) acc2[rt] = z;
    {
        h8 bh[2], bl[2];
        {
            size_t wo = (size_t)(wave * 16 + r) * 128 + g * 8;
            bh[0] = *(const h8*)(W2h + wo);
            bl[0] = *(const h8*)(W2l + wo);
        }
#pragma unroll
        for (int kc = 0; kc < 4; ++kc) {
            const int cur = kc & 1, nxt = cur ^ 1;
            if (kc + 1 < 4) {
                size_t wo = (size_t)(wave * 16 + r) * 128 + (kc + 1) * 32 + g * 8;
                bh[nxt] = *(const h8*)(W2h + wo);
                bl[nxt] = *(const h8*)(W2l + wo);
            }
            const int ko = kc * 32 + g * 8;
#pragma unroll
            for (int rt = 0; rt < 4; ++rt) {
                h8 ah = *(const h8*)(Ah + (rt * 16 + r) * LDA + ko);
                acc2[rt] = mfma2(ah, bh[cur], bl[cur], acc2[rt]);
            }
        }
    }
    // barrier so fp32 writes into agg (LAST) don't race this block's agg reads
    __syncthreads();
    {
        int col = wave * 16 + r;
        float b2 = B2[col];
#pragma unroll
        for (int rt = 0; rt < 4; ++rt)
#pragma unroll
            for (int q = 0; q < 4; ++q) {
                int row = a_base + rt * 16 + g * 4 + q;
                if (row < n_obj) {
                    float v = acc2[rt][q] + b2;
                    if (last) {
                        agg[(size_t)row * 64 + col] = v;   // fp32 result for pooling
                    } else {
                        objh[(size_t)row * 64 + col] = (_Float16)v;
                    }
                }
            }
    }
    if (zero_agg) {
        float4 zz = make_float4(0.f, 0.f, 0.f, 0.f);
#pragma unroll
        for (int i = 0; i < 4; ++i) {
            int f = tid + 256 * i;
            int a = f >> 4, q = f & 15;
            int rg = a_base + a;
            if (rg < n_obj) ((float4*)agg)[(size_t)rg * 16 + q] = zz;
        }
    }
}

__global__ void pool_kernel(const float* __restrict__ obj, const int* __restrict__ batch,
                            float* __restrict__ pooled, int n_obj)
{
    int i = blockIdx.x * 256 + threadIdx.x;
    int row = i >> 4, q = i & 15;
    if (row < n_obj) {
        float4 v = ((const float4*)obj)[(size_t)row * 16 + q];
        int g = batch[row];
        float* p = pooled + g * 64 + 4 * q;
        atomicAdd(p + 0, v.x);
        atomicAdd(p + 1, v.y);
        atomicAdd(p + 2, v.z);
        atomicAdd(p + 3, v.w);
    }
}

__launch_bounds__(128)
__global__ void readout_kernel(const float* __restrict__ pooled,
                               const float* __restrict__ w1, const float* __restrict__ b1,
                               const float* __restrict__ w2, const float* __restrict__ b2,
                               float* __restrict__ out)
{
    int g = blockIdx.x, c = threadIdx.x;
    __shared__ float xs[64];
    __shared__ float red[2];
    if (c < 64) xs[c] = pooled[g * 64 + c];
    __syncthreads();
    float h = b1[c];
#pragma unroll
    for (int k = 0; k < 64; ++k) h = fmaf(xs[k], w1[k * 128 + c], h);
    float v = fmaxf(h, 0.f) * w2[c];
#pragma unroll
    for (int off = 32; off > 0; off >>= 1) v += __shfl_down(v, off);
    if ((c & 63) == 0) red[c >> 6] = v;
    __syncthreads();
    if (c == 0) out[g] = red[0] + red[1] + b2[0];
}

extern "C" void kernel_launch(void* const* d_in, const int* in_sizes, int n_in,
                              void* d_out, int out_size, void* d_ws, size_t ws_size,
                              hipStream_t stream)
{
    const float* w_p1_1 = (const float*)d_in[4];
    const float* b_p1_1 = (const float*)d_in[5];
    const float* w_p1_2 = (const float*)d_in[6];
    const float* b_p1_2 = (const float*)d_in[7];
    const float* w_p2_1 = (const float*)d_in[8];
    const float* b_p2_1 = (const float*)d_in[9];
    const float* w_p2_2 = (const float*)d_in[10];
    const float* b_p2_2 = (const float*)d_in[11];
    const float* w_p3_1 = (const float*)d_in[12];
    const float* b_p3_1 = (const float*)d_in[13];
    const float* w_p3_2 = (const float*)d_in[14];
    const float* b_p3_2 = (const float*)d_in[15];
    const float* w_u1 = (const float*)d_in[16];
    const float* b_u1 = (const float*)d_in[17];
    const float* w_u2 = (const float*)d_in[18];
    const float* b_u2 = (const float*)d_in[19];
    const float* w_r1 = (const float*)d_in[20];
    const float* b_r1 = (const float*)d_in[21];
    const float* w_r2 = (const float*)d_in[22];
    const float* b_r2 = (const float*)d_in[23];
    const int* ei_p1 = (const int*)d_in[24];
    const int* ei_p2 = (const int*)d_in[25];
    const int* ei_p3 = (const int*)d_in[26];
    const int* batch = (const int*)d_in[27];

    const int n_obj = in_sizes[0];
    const int n_p1 = in_sizes[24];
    const int n_p2 = in_sizes[25] / 2;
    const int n_p3 = in_sizes[26] / 3;

    // workspace layout: objh (fp16, n_obj*64) | agg (fp32, n_obj*64) | pooled | hb
    _Float16* objh = (_Float16*)d_ws;
    float* agg = (float*)(objh + (size_t)n_obj * 64);
    float* pooled = agg + (size_t)n_obj * 64;
    _Float16* hb = (_Float16*)(pooled + (size_t)out_size * 64);
    // counts + aconst alias the objh region (consumed by bcast_k before objh is written)
    int* counts = (int*)objh;
    float* ac = (float*)(counts + 6 * (size_t)n_obj);

    const int nb3 = (n_p3 + 63) / 64, nb2 = (n_p2 + 63) / 64, nb1 = (n_p1 + 63) / 64;
    const int pred_smem = 64 * (192 + 8) * 2 + 3 * 64 * 4;  // 26368 B -> ~6 blocks/CU
    (void)ws_size;

    wprep<<<544, 256, 0, stream>>>(w_p1_1, w_p1_2, w_p2_1, w_p2_2, w_p3_1, w_p3_2,
                                   w_u1, w_u2, hb);
    aconst_k<<<3, 256, 0, stream>>>(b_p1_1, w_p1_2, b_p1_2, b_p2_1, w_p2_2, b_p2_2,
                                    b_p3_1, w_p3_2, b_p3_2, ac);
    hipMemsetAsync(counts, 0, 6 * (size_t)n_obj * sizeof(int), stream);
    {
        int tot = n_p1 + 2 * n_p2 + 3 * n_p3;
        hist_k<<<(tot + 255) / 256, 256, 0, stream>>>(ei_p1, ei_p2, ei_p3, counts,
                                                      n_obj, n_p1, n_p2, n_p3);
    }
    bcast_k<<<((size_t)n_obj * 16 + 255) / 256, 256, 0, stream>>>(counts, ac, agg, n_obj);
    // layer 0 update (obj treated as zeros) -> objh; zero agg for layer 1
    update_mfma<1><<<(n_obj + 63) / 64, 256, 0, stream>>>(
        objh, agg, hb + 229376, hb + 245760, b_u1, hb + 262144, hb + 270336, b_u2,
        n_obj, 1, 0);
    for (int l = 1; l < 3; ++l) {
        pred_all<<<nb3 + nb2 + nb1, 256, pred_smem, stream>>>(
            objh, agg, ei_p1, ei_p2, ei_p3, hb,
            b_p1_1, b_p1_2, b_p2_1, b_p2_2, b_p3_1, b_p3_2,
            n_p1, n_p2, n_p3, nb3, nb2);
        update_mfma<0><<<(n_obj + 63) / 64, 256, 0, stream>>>(
            objh, agg, hb + 229376, hb + 245760, b_u1, hb + 262144, hb + 270336, b_u2,
            n_obj, l < 2 ? 1 : 0, l == 2 ? 1 : 0);
    }
    hipMemsetAsync(pooled, 0, (size_t)out_size * 64 * sizeof(float), stream);
    // last update wrote fp32 result into agg
    pool_kernel<<<((size_t)n_obj * 16 + 255) / 256, 256, 0, stream>>>(agg, batch, pooled, n_obj);
    readout_kernel<<<out_size, 128, 0, stream>>>(pooled, w_r1, b_r1, w_r2, b_r2, (float*)d_out);
}